// Round 13
// baseline (886.328 us; speedup 1.0000x reference)
//
#include <hip/hip_runtime.h>
#include <cstdint>
#include <cstddef>

static constexpr int HD = 200;   // hidden
static constexpr int NH = 8;     // heads
static constexpr int CD = 25;    // per-head dim
static constexpr int NL = 4;     // layers

typedef unsigned int u32;
typedef unsigned int u32x4 __attribute__((ext_vector_type(4)));
typedef float f32x4 __attribute__((ext_vector_type(4)));
typedef __bf16 bf16x8 __attribute__((ext_vector_type(8)));

union U8cast { u32x4 u; bf16x8 b; };
__device__ inline bf16x8 as_bf16x8(u32x4 v) { U8cast x; x.u = v; return x.b; }

// truncation split: a = hi + lo + eps, |eps| <= 2^-16 |a|; packs 2 elems per u32.
__device__ inline void split2(float a0, float a1, u32& hi, u32& lo) {
  u32 u0 = __builtin_bit_cast(u32, a0), u1 = __builtin_bit_cast(u32, a1);
  u32 h0 = u0 & 0xffff0000u, h1 = u1 & 0xffff0000u;
  hi = (u0 >> 16) | h1;
  float r0 = a0 - __builtin_bit_cast(float, h0);
  float r1 = a1 - __builtin_bit_cast(float, h1);
  lo = (__builtin_bit_cast(u32, r0) >> 16) | (__builtin_bit_cast(u32, r1) & 0xffff0000u);
}

__device__ inline void mk_frags_r(f32x4 x0, f32x4 x1, bf16x8& hi8, bf16x8& lo8) {
  u32x4 h, l;
  u32 th, tl;
  split2(x0[0], x0[1], th, tl); h[0] = th; l[0] = tl;
  split2(x0[2], x0[3], th, tl); h[1] = th; l[1] = tl;
  split2(x1[0], x1[1], th, tl); h[2] = th; l[2] = tl;
  split2(x1[2], x1[3], th, tl); h[3] = th; l[3] = tl;
  hi8 = as_bf16x8(h); lo8 = as_bf16x8(l);
}

__device__ inline void mk_frags(const float* __restrict__ ap, bf16x8& hi8, bf16x8& lo8) {
  mk_frags_r(*(const f32x4*)ap, *(const f32x4*)(ap + 4), hi8, lo8);
}

// ---------------- CSR build ----------------
__global__ __launch_bounds__(256) void k_hist(const int* __restrict__ dst, int* __restrict__ cnt, int E) {
  int e = blockIdx.x * 256 + threadIdx.x;
  if (e < E) atomicAdd(&cnt[dst[e]], 1);
}

__global__ __launch_bounds__(256) void k_scan1(const int* __restrict__ cnt, int* __restrict__ off,
                                               int* __restrict__ partial, int N) {
  __shared__ int sm[256];
  int t = threadIdx.x, i = blockIdx.x * 256 + t;
  int v = (i < N) ? cnt[i] : 0;
  sm[t] = v; __syncthreads();
  for (int o = 1; o < 256; o <<= 1) {
    int add = (t >= o) ? sm[t - o] : 0;
    __syncthreads();
    sm[t] += add;
    __syncthreads();
  }
  if (i < N) off[i] = sm[t] - v;
  if (t == 255) partial[blockIdx.x] = sm[255];
}

__global__ __launch_bounds__(512) void k_scan2(int* __restrict__ partial, int nb, int* __restrict__ off, int N) {
  __shared__ int sm[512];
  int t = threadIdx.x;
  int v = (t < nb) ? partial[t] : 0;
  sm[t] = v; __syncthreads();
  for (int o = 1; o < 512; o <<= 1) {
    int add = (t >= o) ? sm[t - o] : 0;
    __syncthreads();
    sm[t] += add;
    __syncthreads();
  }
  if (t < nb) partial[t] = sm[t] - v;
  if (t == 511) off[N] = sm[511];
}

__global__ __launch_bounds__(256) void k_scan3(int* __restrict__ off, const int* __restrict__ partial, int N) {
  int i = blockIdx.x * 256 + threadIdx.x;
  if (i < N) off[i] += partial[i >> 8];
}

__global__ __launch_bounds__(256) void k_scatter(const int* __restrict__ dst, const int* __restrict__ off,
                                                 int* __restrict__ cur, int* __restrict__ eid, int E) {
  int e = blockIdx.x * 256 + threadIdx.x;
  if (e < E) {
    int d = dst[e];
    int p = atomicAdd(&cur[d], 1);
    eid[off[d] + p] = e;
  }
}

__global__ __launch_bounds__(256) void k_sort(const int* __restrict__ off, int* __restrict__ eid, int N) {
  int n = blockIdx.x * 256 + threadIdx.x;
  if (n >= N) return;
  int o0 = off[n], o1 = off[n + 1];
  for (int i = o0 + 1; i < o1; ++i) {
    int v = eid[i]; int j = i - 1;
    while (j >= o0 && eid[j] > v) { eid[j + 1] = eid[j]; --j; }
    eid[j + 1] = v;
  }
}

// ---------------- edge-attention precompute (algebraic reductions) ----------------
__global__ __launch_bounds__(128) void k_meanea(const float* __restrict__ ea, const int* __restrict__ off,
                                                const int* __restrict__ eid, float* __restrict__ mea, int N) {
  int n = blockIdx.x * 128 + threadIdx.x;
  if (n >= N) return;
  int o0 = off[n], o1 = off[n + 1];
  float s0 = 0, s1 = 0, s2 = 0, s3 = 0, s4 = 0, s5 = 0;
  for (int p = o0; p < o1; ++p) {
    const float* r = ea + (size_t)eid[p] * 6;
    s0 += r[0]; s1 += r[1]; s2 += r[2]; s3 += r[3]; s4 += r[4]; s5 += r[5];
  }
  float inv = (o1 > o0) ? 1.f / (float)(o1 - o0) : 0.f;
  float* m = mea + (size_t)n * 6;
  m[0] = s0 * inv; m[1] = s1 * inv; m[2] = s2 * inv; m[3] = s3 * inv; m[4] = s4 * inv; m[5] = s5 * inv;
}

// we[l][k][h]   = sum_c lin_edge_w[l][k][h*25+c] * att_edge[l][h][c]
// wsrc[l][k][h] = sum_c lin_w[l][k][h*25+c]      * att_src[l][h][c]
// wdst[l][k][h] = sum_c lin_w[l][k][h*25+c]      * att_dst[l][h][c]
__global__ __launch_bounds__(256) void k_we2(const float* __restrict__ lew, const float* __restrict__ linw,
                                             const float* __restrict__ aeg, const float* __restrict__ asg,
                                             const float* __restrict__ adg, float* __restrict__ we,
                                             float* __restrict__ wsrc, float* __restrict__ wdst) {
  int tid = blockIdx.x * 256 + threadIdx.x;
  if (tid >= NL * HD * 8) return;
  int l = tid / (HD * 8); int r = tid % (HD * 8); int k = r >> 3; int hh = r & 7;
  const float* We = lew + (size_t)l * HD * HD + (size_t)k * HD + hh * CD;
  const float* Wl = linw + (size_t)l * HD * HD + (size_t)k * HD + hh * CD;
  const float* ae = aeg + l * NH * CD + hh * CD;
  const float* as = asg + l * NH * CD + hh * CD;
  const float* ad = adg + l * NH * CD + hh * CD;
  float s0 = 0.f, s1 = 0.f, s2 = 0.f;
#pragma unroll
  for (int c = 0; c < CD; ++c) {
    float we_ = We[c], wl_ = Wl[c];
    s0 += we_ * ae[c]; s1 += wl_ * as[c]; s2 += wl_ * ad[c];
  }
  we[tid] = s0; wsrc[tid] = s1; wdst[tid] = s2;   // layout l*1600 + k*8 + h
}

// M[l][f][h] = sum_k edge_emb_w[f][k] * we[l][k][h];  cv[l][h] = sum_k edge_emb_b[k]*we[l][k][h]
__global__ __launch_bounds__(256) void k_M(const float* __restrict__ ew, const float* __restrict__ eb,
                                           const float* __restrict__ we, float* __restrict__ Mm,
                                           float* __restrict__ cv) {
  int tid = threadIdx.x;
  if (tid < NL * 6 * 8) {
    int l = tid / 48, r = tid % 48, f = r / 8, hh = r % 8;
    float s = 0.f;
    for (int k = 0; k < HD; ++k) s += ew[f * HD + k] * we[l * 1600 + k * 8 + hh];
    Mm[tid] = s;   // l*48 + f*8 + hh
  } else if (tid < NL * 6 * 8 + NL * 8) {
    int u = tid - NL * 6 * 8, l = u / 8, hh = u % 8;
    float s = 0.f;
    for (int k = 0; k < HD; ++k) s += eb[k] * we[l * 1600 + k * 8 + hh];
    cv[u] = s;
  }
}

// self-loop attention logit contribution ae_s for all layers
__global__ __launch_bounds__(256) void k_ae_self(const float* __restrict__ mea, const int* __restrict__ cnt,
                                                 const float* __restrict__ Mm, const float* __restrict__ cv,
                                                 float* __restrict__ aes, int N) {
  int n = blockIdx.x * 256 + threadIdx.x;
  if (n >= N) return;
  bool has = cnt[n] > 0;
  float v[6];
#pragma unroll
  for (int f = 0; f < 6; ++f) v[f] = mea[(size_t)n * 6 + f];
  for (int l = 0; l < NL; ++l)
#pragma unroll
    for (int hh = 0; hh < 8; ++hh) {
      float s = 0.f;
      if (has) {
        s = cv[l * 8 + hh];
#pragma unroll
        for (int f = 0; f < 6; ++f) s += v[f] * Mm[l * 48 + f * 8 + hh];
      }
      aes[(size_t)l * N * 8 + (size_t)n * 8 + hh] = s;
    }
}

// one-time: CSR-ordered src index + all-layer layer-invariant edge logit part
__global__ __launch_bounds__(256) void k_aep(const float* __restrict__ ea, const int* __restrict__ eid,
                                             const int* __restrict__ esrc, const float* __restrict__ Mm,
                                             const float* __restrict__ cv, int* __restrict__ src_csr,
                                             float* __restrict__ aep, int E) {
  int p = blockIdx.x * 256 + threadIdx.x;
  if (p >= E) return;
  int e = eid[p];
  src_csr[p] = esrc[e];
  float v[6];
  const float* er = ea + (size_t)e * 6;
#pragma unroll
  for (int f = 0; f < 6; ++f) v[f] = er[f];
#pragma unroll
  for (int l = 0; l < NL; ++l) {
#pragma unroll
    for (int hh = 0; hh < 8; ++hh) {
      float s = cv[l * 8 + hh];
#pragma unroll
      for (int f = 0; f < 6; ++f) s += v[f] * Mm[l * 48 + f * 8 + hh];
      aep[(size_t)l * E * 8 + (size_t)p * 8 + hh] = s;
    }
  }
}

// ---------------- weight split v5: LDS-image layout ----------------
__global__ __launch_bounds__(256) void k_split5(const float* __restrict__ W, u32* __restrict__ out,
                                                int K, int nsteps, int inStride,
                                                const float* __restrict__ wsrc,
                                                const float* __restrict__ wdst) {
  int l = blockIdx.y;
  int tot = nsteps * 7168;
  int idx = blockIdx.x * 256 + threadIdx.x;
  if (idx >= tot) return;
  int ks = idx / 7168, r = idx % 7168;
  int plane = r / 3584, r2 = r % 3584;
  int g = r2 >> 2, j = r2 & 3;
  int c = g >> 2, kg = g & 3;
  int k = ks * 32 + kg * 8 + j * 2;
  float a0 = 0.f, a1 = 0.f;
  if (c < HD) {
    if (k < K) {
      const float* Wl = W + (size_t)l * inStride;
      a0 = Wl[(size_t)k * HD + c];
      a1 = Wl[(size_t)(k + 1) * HD + c];
    }
  } else if (wsrc && c < 216 && k < K) {
    const float* src = ((c < 208) ? wsrc : wdst) + (size_t)l * 1600;
    int hh = (c - 200) & 7;
    a0 = src[k * 8 + hh];
    a1 = src[(k + 1) * 8 + hh];
  }
  u32 hi, lo; split2(a0, a1, hi, lo);
  out[(size_t)l * tot + idx] = (plane == 0) ? hi : lo;
}

// merged readout split: readout_w [4][200][200] -> LDS-image [25 ks][7168 u32], K global 0..799
__global__ __launch_bounds__(256) void k_split_ro5(const float* __restrict__ W, u32* __restrict__ out) {
  int idx = blockIdx.x * 256 + threadIdx.x;
  if (idx >= 25 * 7168) return;
  int ks = idx / 7168, r = idx % 7168;
  int plane = r / 3584, r2 = r % 3584;
  int g = r2 >> 2, j = r2 & 3;
  int c = g >> 2, kg = g & 3;
  int k = ks * 32 + kg * 8 + j * 2;
  float a0 = 0.f, a1 = 0.f;
  if (c < HD) {
    int lsrc = k / HD, kl = k % HD;
    const float* Wl = W + (size_t)lsrc * HD * HD;
    a0 = Wl[(size_t)kl * HD + c];
    a1 = Wl[(size_t)(kl + 1) * HD + c];
  }
  u32 hi, lo; split2(a0, a1, hi, lo);
  out[idx] = (plane == 0) ? hi : lo;
}

// summed readout bias
__global__ __launch_bounds__(256) void k_bsum(const float* __restrict__ rb, float* __restrict__ out) {
  int t = threadIdx.x;
  if (t < HD) out[t] = rb[t] + rb[HD + t] + rb[2 * HD + t] + rb[3 * HD + t];
}

// head W1 split: head_w1 [5][200][100] -> planes [t][112 cols][224 k] bf16
__global__ __launch_bounds__(256) void k_split_hw(const float* __restrict__ W, u32* __restrict__ hiT,
                                                  u32* __restrict__ loT) {
  int t = blockIdx.y;
  int idx = blockIdx.x * 256 + threadIdx.x;
  if (idx >= 112 * 112) return;
  int c = idx / 112, kp = (idx % 112) * 2;
  const float* Wt = W + (size_t)t * HD * 100;
  float a0 = (c < 100 && kp < HD) ? Wt[(size_t)kp * 100 + c] : 0.f;
  float a1 = (c < 100 && kp + 1 < HD) ? Wt[(size_t)(kp + 1) * 100 + c] : 0.f;
  u32 hi, lo; split2(a0, a1, hi, lo);
  size_t ob = (size_t)t * 112 * 112 + idx;
  hiT[ob] = hi; loT[ob] = lo;
}

// ---------------- MFMA GEMM v5 (split-bf16, B double-buffered in LDS via global_load_lds) ----
template<int NSTEPS, bool ATTN>
__global__ __launch_bounds__(256) void k_gemm_v5(const float* __restrict__ A, const u32* __restrict__ Bpk,
                                                 const float* __restrict__ bias, float* __restrict__ C,
                                                 float* __restrict__ aS, float* __restrict__ aD,
                                                 int M, int K) {
  constexpr int NT = 7;
  __shared__ u32 smem[2 * 7168];
  const int tid = threadIdx.x;
  const int lane = tid & 63;
  const int w = tid >> 6;
  const int wm = w >> 1, wn = w & 1;
  const int lr = lane & 15, kg = lane >> 4;
  const int kg8 = kg * 8;

  const int rowA0 = blockIdx.x * 64 + wm * 32 + lr;
  const int rowA1 = rowA0 + 16;
  const float* Ap0 = A + (size_t)((rowA0 < M) ? rowA0 : (M - 1)) * K;
  const float* Ap1 = A + (size_t)((rowA1 < M) ? rowA1 : (M - 1)) * K;
  const int colbase = wn * 112;
  const int dsbase = (colbase + lr) * 16 + kg * 4;

  f32x4 acc[2][NT];
#pragma unroll
  for (int mt = 0; mt < 2; ++mt)
#pragma unroll
    for (int t = 0; t < NT; ++t) acc[mt][t] = (f32x4)0.f;

#pragma unroll
  for (int i = 0; i < 7; ++i) {
    const int chunk = i * 4 + w;
    __builtin_amdgcn_global_load_lds((const void*)(Bpk + chunk * 256 + lane * 4),
                                     (void*)(smem + chunk * 256), 16, 0, 0);
  }
  f32x4 a0c, a0d, a1c, a1d;
  a0c = *(const f32x4*)(Ap0 + kg8); a0d = *(const f32x4*)(Ap0 + kg8 + 4);
  a1c = *(const f32x4*)(Ap1 + kg8); a1d = *(const f32x4*)(Ap1 + kg8 + 4);
  __syncthreads();

  int cur = 0;
  for (int ks = 0; ks < NSTEPS; ++ks) {
    const bool more = (ks + 1) < NSTEPS;
    if (more) {
      const u32* src = Bpk + (size_t)(ks + 1) * 7168;
      u32* dst = smem + (cur ^ 1) * 7168;
#pragma unroll
      for (int i = 0; i < 7; ++i) {
        const int chunk = i * 4 + w;
        __builtin_amdgcn_global_load_lds((const void*)(src + chunk * 256 + lane * 4),
                                         (void*)(dst + chunk * 256), 16, 0, 0);
      }
    }
    bf16x8 ah0, al0, ah1, al1;
    {
      const int k0 = ks * 32 + kg8;
      if (k0 < K) {
        mk_frags_r(a0c, a0d, ah0, al0);
        mk_frags_r(a1c, a1d, ah1, al1);
      } else {
        u32x4 zz; zz[0] = 0; zz[1] = 0; zz[2] = 0; zz[3] = 0;
        ah0 = as_bf16x8(zz); al0 = ah0; ah1 = ah0; al1 = ah0;
      }
    }
    if (more) {
      const int k0n = (ks + 1) * 32 + kg8;
      if (k0n < K) {
        a0c = *(const f32x4*)(Ap0 + k0n); a0d = *(const f32x4*)(Ap0 + k0n + 4);
        a1c = *(const f32x4*)(Ap1 + k0n); a1d = *(const f32x4*)(Ap1 + k0n + 4);
      }
    }
    const u32* bb = smem + cur * 7168;
#pragma unroll
    for (int t = 0; t < NT; ++t) {
      bf16x8 bh = as_bf16x8(*(const u32x4*)(bb + dsbase + t * 256));
      bf16x8 bl = as_bf16x8(*(const u32x4*)(bb + 3584 + dsbase + t * 256));
      acc[0][t] = __builtin_amdgcn_mfma_f32_16x16x32_bf16(ah0, bh, acc[0][t], 0, 0, 0);
      acc[0][t] = __builtin_amdgcn_mfma_f32_16x16x32_bf16(ah0, bl, acc[0][t], 0, 0, 0);
      acc[0][t] = __builtin_amdgcn_mfma_f32_16x16x32_bf16(al0, bh, acc[0][t], 0, 0, 0);
      acc[1][t] = __builtin_amdgcn_mfma_f32_16x16x32_bf16(ah1, bh, acc[1][t], 0, 0, 0);
      acc[1][t] = __builtin_amdgcn_mfma_f32_16x16x32_bf16(ah1, bl, acc[1][t], 0, 0, 0);
      acc[1][t] = __builtin_amdgcn_mfma_f32_16x16x32_bf16(al1, bh, acc[1][t], 0, 0, 0);
    }
    __syncthreads();
    cur ^= 1;
  }

#pragma unroll
  for (int mt = 0; mt < 2; ++mt) {
    const int rbase = blockIdx.x * 64 + wm * 32 + mt * 16 + kg * 4;
#pragma unroll
    for (int t = 0; t < NT; ++t) {
      const int c = colbase + t * 16 + lr;
      if (c < HD) {
        const float badd = bias ? bias[c] : 0.f;
#pragma unroll
        for (int j = 0; j < 4; ++j) {
          const int r = rbase + j;
          if (r < M) C[(size_t)r * HD + c] = acc[mt][t][j] + badd;
        }
      } else if (ATTN && c < 216) {
        float* dstp = (c < 208) ? aS : aD;
        const int hh = (c - 200) & 7;
#pragma unroll
        for (int j = 0; j < 4; ++j) {
          const int r = rbase + j;
          if (r < M) dstp[(size_t)r * 8 + hh] = acc[mt][t][j];
        }
      }
    }
  }
}

// ---------------- head GEMM fused with w2 dot + sigmoid: out[t][g] directly ----------------
__global__ __launch_bounds__(128) void k_headgemm(const float* __restrict__ A, const u32* __restrict__ hwHi,
                                                  const u32* __restrict__ hwLo, const float* __restrict__ b1,
                                                  const float* __restrict__ w2, const float* __restrict__ b2,
                                                  float* __restrict__ out, int M) {
  const int task = blockIdx.y;
  const int lane = threadIdx.x & 63;
  const int w = threadIdx.x >> 6;
  const int lr = lane & 15, kg = lane >> 4;
  const int K = HD;
  const int nStep = 7;
  const int bstride = 112;

  const int rowA0 = blockIdx.x * 64 + w * 32 + lr;
  const int rowA1 = rowA0 + 16;
  const float* Ap0 = A + (size_t)((rowA0 < M) ? rowA0 : (M - 1)) * K;
  const float* Ap1 = A + (size_t)((rowA1 < M) ? rowA1 : (M - 1)) * K;
  const u32* BhT = hwHi + (size_t)task * 112 * 112;
  const u32* BlT = hwLo + (size_t)task * 112 * 112;

  f32x4 acc[2][7];
#pragma unroll
  for (int mt = 0; mt < 2; ++mt)
#pragma unroll
    for (int t = 0; t < 7; ++t) acc[mt][t] = (f32x4)0.f;

  u32x4 zz; zz[0] = 0; zz[1] = 0; zz[2] = 0; zz[3] = 0;
  const bf16x8 zfrag = as_bf16x8(zz);

  for (int ks = 0; ks < nStep; ++ks) {
    const int kb = ks * 32;
    const int k0 = kb + kg * 8;
    bf16x8 ah0, al0, ah1, al1;
    if (k0 < K) {
      mk_frags(Ap0 + k0, ah0, al0);
      mk_frags(Ap1 + k0, ah1, al1);
    } else {
      ah0 = zfrag; al0 = zfrag; ah1 = zfrag; al1 = zfrag;
    }
    const u32* Bh = BhT + (kb >> 1) + kg * 4;
    const u32* Bl = BlT + (kb >> 1) + kg * 4;
#pragma unroll
    for (int t = 0; t < 7; ++t) {
      const size_t cb = (size_t)(t * 16 + lr) * bstride;
      bf16x8 bh = as_bf16x8(*(const u32x4*)(Bh + cb));
      bf16x8 bl = as_bf16x8(*(const u32x4*)(Bl + cb));
      acc[0][t] = __builtin_amdgcn_mfma_f32_16x16x32_bf16(ah0, bh, acc[0][t], 0, 0, 0);
      acc[0][t] = __builtin_amdgcn_mfma_f32_16x16x32_bf16(ah0, bl, acc[0][t], 0, 0, 0);
      acc[0][t] = __builtin_amdgcn_mfma_f32_16x16x32_bf16(al0, bh, acc[0][t], 0, 0, 0);
      acc[1][t] = __builtin_amdgcn_mfma_f32_16x16x32_bf16(ah1, bh, acc[1][t], 0, 0, 0);
      acc[1][t] = __builtin_amdgcn_mfma_f32_16x16x32_bf16(ah1, bl, acc[1][t], 0, 0, 0);
      acc[1][t] = __builtin_amdgcn_mfma_f32_16x16x32_bf16(al1, bh, acc[1][t], 0, 0, 0);
    }
  }

  float w2v[7], b1v[7];
#pragma unroll
  for (int t = 0; t < 7; ++t) {
    const int c = t * 16 + lr;
    w2v[t] = (c < 100) ? w2[task * 100 + c] : 0.f;
    b1v[t] = (c < 100) ? b1[task * 100 + c] : 0.f;
  }
  const bool sig = (task == 0) | (task == 3) | (task == 4);
#pragma unroll
  for (int mt = 0; mt < 2; ++mt) {
    const int rbase = blockIdx.x * 64 + w * 32 + mt * 16 + kg * 4;
#pragma unroll
    for (int j = 0; j < 4; ++j) {
      float part = 0.f;
#pragma unroll
      for (int t = 0; t < 7; ++t) {
        const int c = t * 16 + lr;
        if (c < 100) {
          float v = acc[mt][t][j] + b1v[t];
          v = v > 0.f ? v : 0.f;
          part += v * w2v[t];
        }
      }
      part += __shfl_xor(part, 1);
      part += __shfl_xor(part, 2);
      part += __shfl_xor(part, 4);
      part += __shfl_xor(part, 8);
      const int r = rbase + j;
      if (lr == 0 && r < M) {
        float zv = part + b2[task];
        out[(size_t)task * M + r] = sig ? 1.f / (1.f + expf(-zv)) : zv;
      }
    }
  }
}

// ---------------- aggregation v6: block per graph (4 waves), fused pool, batched gather ----------
// Same math/order as aggr4; the chunk-0 value gathers are issued as 8 independent
// predicated f32x4 loads BEFORE the FMA chain (latency amortized ~8x).
__global__ __launch_bounds__(256) void k_aggr6(const float* __restrict__ xs, const float* __restrict__ a_src,
                                               const float* __restrict__ a_dst, const float* __restrict__ aep,
                                               const float* __restrict__ aes, const float* __restrict__ gb,
                                               const int* __restrict__ off, const int* __restrict__ src_csr,
                                               const int* __restrict__ gstart, float* __restrict__ h_out,
                                               float* __restrict__ pooled, int coff, int writeH) {
  __shared__ float red[4][HD];
  const int g = blockIdx.x;
  const int lane = threadIdx.x & 63;
  const int wv = threadIdx.x >> 6;
  const int s0g = gstart[g], s1g = gstart[g + 1];
  const int h = lane & 7, q = lane >> 3;
  const int c0 = lane * 4;                 // cols c0..c0+3 (lanes 0..49)
  const bool val4 = lane < 50;
  const int h0 = val4 ? (c0 / 25) : 0;
  const int h3 = val4 ? ((c0 + 3) / 25) : 0;
  const int bcut = 25 * (h0 + 1) - c0;     // #elems in head h0

  f32x4 pacc = (f32x4)0.f;

  for (int node = s0g + wv; node < s1g; node += 4) {
    const int o0 = off[node], o1 = off[node + 1];
    // prefetch self row early (independent of everything below)
    f32x4 xself = (f32x4)0.f;
    if (val4) xself = *(const f32x4*)(xs + (size_t)node * HD + c0);

    const float adst_h = a_dst[(size_t)node * 8 + h];
    float lself = 0.f;
    if (lane < 8) {
      float v = a_src[(size_t)node * 8 + lane] + a_dst[(size_t)node * 8 + lane]
              + aes[(size_t)node * 8 + lane];
      lself = (v >= 0.f) ? v : 0.2f * v;
    }
    // chunk 0 logits in registers (deg <= 8 fast path)
    const int p0i = o0 + q;
    const bool v0 = p0i < o1;
    int s0 = 0; float lg0 = -1e30f;
    if (v0) {
      s0 = src_csr[p0i];
      float av = a_src[(size_t)s0 * 8 + h] + adst_h + aep[(size_t)p0i * 8 + h];
      lg0 = (av >= 0.f) ? av : 0.2f * av;
    }
    float mx = lg0;
    for (int pb = o0 + 8; pb < o1; pb += 8) {
      int p = pb + q;
      if (p < o1) {
        int s = src_csr[p];
        float av = a_src[(size_t)s * 8 + h] + adst_h + aep[(size_t)p * 8 + h];
        av = (av >= 0.f) ? av : 0.2f * av;
        mx = fmaxf(mx, av);
      }
    }
    mx = fmaxf(mx, __shfl_xor(mx, 8));
    mx = fmaxf(mx, __shfl_xor(mx, 16));
    mx = fmaxf(mx, __shfl_xor(mx, 32));
    mx = fmaxf(mx, __shfl(lself, h));

    const int cnt0 = (o1 - o0) > 8 ? 8 : (o1 - o0);
    // batched gather: shuffle all src indices, then issue all row loads back-to-back
    int sjr[8];
#pragma unroll
    for (int j = 0; j < 8; ++j) sjr[j] = __shfl(s0, j * 8);
    f32x4 xvr[8];
#pragma unroll
    for (int j = 0; j < 8; ++j)
      if (val4 && j < cnt0) xvr[j] = *(const f32x4*)(xs + (size_t)sjr[j] * HD + c0);

    f32x4 acc = (f32x4)0.f;
    float wsum = 0.f;
    // chunk 0 FMA chain (identical j order)
    {
      float wgt = v0 ? expf(lg0 - mx) : 0.f;
      wsum += wgt;
#pragma unroll
      for (int j = 0; j < 8; ++j) {
        if (j < cnt0) {
          float wA = __shfl(wgt, j * 8 + h0);
          float wB = __shfl(wgt, j * 8 + h3);
          if (val4) {
#pragma unroll
            for (int i = 0; i < 4; ++i)
              acc[i] += ((i < bcut) ? wA : wB) * xvr[j][i];
          }
        }
      }
    }
    // remaining chunks (deg > 8, rare)
    for (int pb = o0 + 8; pb < o1; pb += 8) {
      int p = pb + q;
      bool valid = p < o1;
      float wgt = 0.f; int s = 0;
      if (valid) {
        s = src_csr[p];
        float av = a_src[(size_t)s * 8 + h] + adst_h + aep[(size_t)p * 8 + h];
        av = (av >= 0.f) ? av : 0.2f * av;
        wgt = expf(av - mx);
      }
      wsum += wgt;
      int cnt = o1 - pb; if (cnt > 8) cnt = 8;
      int sjr2[8];
#pragma unroll
      for (int j = 0; j < 8; ++j) sjr2[j] = __shfl(s, j * 8);
      f32x4 xvr2[8];
#pragma unroll
      for (int j = 0; j < 8; ++j)
        if (val4 && j < cnt) xvr2[j] = *(const f32x4*)(xs + (size_t)sjr2[j] * HD + c0);
#pragma unroll
      for (int j = 0; j < 8; ++j) {
        if (j < cnt) {
          float wA = __shfl(wgt, j * 8 + h0);
          float wB = __shfl(wgt, j * 8 + h3);
          if (val4) {
#pragma unroll
            for (int i = 0; i < 4; ++i)
              acc[i] += ((i < bcut) ? wA : wB) * xvr2[j][i];
          }
        }
      }
    }
    wsum += __shfl_xor(wsum, 8);
    wsum += __shfl_xor(wsum, 16);
    wsum += __shfl_xor(wsum, 32);
    // self contribution last (reference concat order)
    float wself = (lane < 8) ? expf(lself - mx) : 0.f;
    {
      float wA = __shfl(wself, h0);
      float wB = __shfl(wself, h3);
      if (val4) {
#pragma unroll
        for (int i = 0; i < 4; ++i)
          acc[i] += ((i < bcut) ? wA : wB) * xself[i];
      }
      wsum += __shfl(wself, h);
    }
    float denA = __shfl(wsum, h0) + 1e-16f;
    float denB = __shfl(wsum, h3) + 1e-16f;
    if (val4) {
      f32x4 gv = *(const f32x4*)(gb + c0);
      f32x4 hv;
#pragma unroll
      for (int i = 0; i < 4; ++i)
        hv[i] = acc[i] / ((i < bcut) ? denA : denB) + gv[i];
      if (writeH) *(f32x4*)(h_out + (size_t)node * HD + c0) = hv;
      pacc += hv;
    }
  }
  // cross-wave pooled reduction -> pooled[g][coff + c]
  if (val4) *(f32x4*)(&red[wv][c0]) = pacc;
  __syncthreads();
  if (wv == 0 && val4) {
    f32x4 r0 = *(const f32x4*)(&red[0][c0]);
    f32x4 r1 = *(const f32x4*)(&red[1][c0]);
    f32x4 r2 = *(const f32x4*)(&red[2][c0]);
    f32x4 r3 = *(const f32x4*)(&red[3][c0]);
    f32x4 s = (r0 + r1) + (r2 + r3);
    *(f32x4*)(pooled + (size_t)g * 800 + coff + c0) = s;
  }
}

__global__ __launch_bounds__(256) void k_gstart(const int* __restrict__ batch, int* __restrict__ gstart,
                                                int N, int G) {
  int i = blockIdx.x * 256 + threadIdx.x;
  if (i >= N) return;
  int b = batch[i];
  int pb = (i == 0) ? -1 : batch[i - 1];
  for (int g = pb + 1; g <= b; ++g) gstart[g] = i;
  if (i == N - 1) for (int g = b + 1; g <= G; ++g) gstart[g] = N;
}

extern "C" void kernel_launch(void* const* d_in, const int* in_sizes, int n_in,
                              void* d_out, int out_size, void* d_ws, size_t ws_size,
                              hipStream_t stream) {
  const float* x         = (const float*)d_in[0];
  const float* edge_attr = (const float*)d_in[1];
  const float* node_w    = (const float*)d_in[2];
  const float* node_b    = (const float*)d_in[3];
  const float* edge_w    = (const float*)d_in[4];
  const float* edge_b    = (const float*)d_in[5];
  const float* lin_w     = (const float*)d_in[6];
  const float* lin_edge_w= (const float*)d_in[7];
  const float* att_src   = (const float*)d_in[8];
  const float* att_dst   = (const float*)d_in[9];
  const float* att_edge  = (const float*)d_in[10];
  const float* gat_bias  = (const float*)d_in[11];
  const float* readout_w = (const float*)d_in[12];
  const float* readout_b = (const float*)d_in[13];
  const float* head_w1   = (const float*)d_in[14];
  const float* head_b1   = (const float*)d_in[15];
  const float* head_w2   = (const float*)d_in[16];
  const float* head_b2   = (const float*)d_in[17];
  const int*   edge_index= (const int*)d_in[18];
  const int*   batch     = (const int*)d_in[19];

  const int N = in_sizes[0] / 64;
  const int E = in_sizes[1] / 6;
  const int G = out_size / 5;
  const int* srcI = edge_index;
  const int* dstI = edge_index + E;

  char* wsb = (char*)d_ws;
  size_t o = 0;
  auto alloc = [&](size_t bytes) -> void* {
    void* p = wsb + o;
    o = (o + bytes + 255) & ~(size_t)255;
    return p;
  };
  float* h       = (float*)alloc((size_t)N * HD * 4);
  float* xs      = (float*)alloc((size_t)N * HD * 4);
  float* a_src   = (float*)alloc((size_t)N * 8 * 4);
  float* a_dst   = (float*)alloc((size_t)N * 8 * 4);
  float* aep     = (float*)alloc((size_t)NL * E * 8 * 4);
  int*   src_csr = (int*)alloc((size_t)E * 4);
  float* ae_s    = (float*)alloc((size_t)NL * N * 8 * 4);
  float* mean_ea = (float*)alloc((size_t)N * 6 * 4);
  float* we      = (float*)alloc((size_t)NL * HD * 8 * 4);
  float* wsrc    = (float*)alloc((size_t)NL * HD * 8 * 4);
  float* wdst    = (float*)alloc((size_t)NL * HD * 8 * 4);
  float* Mm      = (float*)alloc((size_t)NL * 6 * 8 * 4);
  float* cv      = (float*)alloc((size_t)NL * 8 * 4);
  int* cnt       = (int*)alloc((size_t)N * 4);
  int* cur       = (int*)alloc((size_t)N * 4);
  int* off       = (int*)alloc((size_t)(N + 1) * 4);
  int* partial   = (int*)alloc(512 * 4);
  int* eid       = (int*)alloc((size_t)E * 4);
  int* gstart    = (int*)alloc((size_t)(G + 1) * 4);
  float* pooled4 = (float*)alloc((size_t)G * 800 * 4);
  float* readouts= (float*)alloc((size_t)G * HD * 4);
  float* bsum    = (float*)alloc(HD * 4);
  // pre-split LDS-image weight buffers (u32 = 2 bf16; 7168 u32 per K-step)
  u32* nodePk    = (u32*)alloc((size_t)2 * 7168 * 4);
  u32* linPk     = (u32*)alloc((size_t)NL * 7 * 7168 * 4);
  u32* roPk      = (u32*)alloc((size_t)25 * 7168 * 4);
  u32* hw_hi     = (u32*)alloc((size_t)5 * 112 * 112 * 4);
  u32* hw_lo     = (u32*)alloc((size_t)5 * 112 * 112 * 4);
  (void)ws_size; (void)n_in;

  hipMemsetAsync(cnt, 0, (size_t)N * 4, stream);
  hipMemsetAsync(cur, 0, (size_t)N * 4, stream);

  int nb = (N + 255) / 256;
  k_hist<<<(E + 255) / 256, 256, 0, stream>>>(dstI, cnt, E);
  k_scan1<<<nb, 256, 0, stream>>>(cnt, off, partial, N);
  k_scan2<<<1, 512, 0, stream>>>(partial, nb, off, N);
  k_scan3<<<nb, 256, 0, stream>>>(off, partial, N);
  k_scatter<<<(E + 255) / 256, 256, 0, stream>>>(dstI, off, cur, eid, E);
  k_sort<<<nb, 256, 0, stream>>>(off, eid, N);
  k_meanea<<<(N + 127) / 128, 128, 0, stream>>>(edge_attr, off, eid, mean_ea, N);
  k_we2<<<(NL * HD * 8 + 255) / 256, 256, 0, stream>>>(lin_edge_w, lin_w, att_edge, att_src, att_dst,
                                                       we, wsrc, wdst);
  k_M<<<1, 256, 0, stream>>>(edge_w, edge_b, we, Mm, cv);
  k_ae_self<<<(N + 255) / 256, 256, 0, stream>>>(mean_ea, cnt, Mm, cv, ae_s, N);
  k_aep<<<(E + 255) / 256, 256, 0, stream>>>(edge_attr, eid, srcI, Mm, cv, src_csr, aep, E);

  // weight splits
  {
    k_split5<<<dim3((2 * 7168 + 255) / 256, 1), 256, 0, stream>>>(node_w, nodePk, 64, 2, 0,
                                                                  nullptr, nullptr);
    k_split5<<<dim3((7 * 7168 + 255) / 256, NL), 256, 0, stream>>>(lin_w, linPk, HD, 7, HD * HD,
                                                                   wsrc, wdst);
    k_split_ro5<<<(25 * 7168 + 255) / 256, 256, 0, stream>>>(readout_w, roPk);
    k_bsum<<<1, 256, 0, stream>>>(readout_b, bsum);
    dim3 g3((112 * 112 + 255) / 256, 5);
    k_split_hw<<<g3, 256, 0, stream>>>(head_w1, hw_hi, hw_lo);
  }

  const int gemmBlocks = (N + 63) / 64;
  k_gemm_v5<2, false><<<gemmBlocks, 256, 0, stream>>>(x, nodePk, node_b, h, nullptr, nullptr, N, 64);
  k_gstart<<<nb, 256, 0, stream>>>(batch, gstart, N, G);

  for (int l = 0; l < NL; ++l) {
    k_gemm_v5<7, true><<<gemmBlocks, 256, 0, stream>>>(h, linPk + (size_t)l * 7 * 7168,
                                                       nullptr, xs, a_src, a_dst, N, HD);
    k_aggr6<<<G, 256, 0, stream>>>(xs, a_src, a_dst, aep + (size_t)l * E * 8,
                                   ae_s + (size_t)l * N * 8, gat_bias + l * HD,
                                   off, src_csr, gstart, h, pooled4, l * HD, (l < NL - 1) ? 1 : 0);
  }
  // merged readout: readouts = pooled4 @ roW4 + sum_l b_l   (K = 800)
  k_gemm_v5<25, false><<<(G + 63) / 64, 256, 0, stream>>>(pooled4, roPk, bsum, readouts,
                                                          nullptr, nullptr, G, 800);
  {
    dim3 hg((G + 63) / 64, 5);
    k_headgemm<<<hg, 128, 0, stream>>>(readouts, hw_hi, hw_lo, head_b1, head_w2, head_b2,
                                       (float*)d_out, G);
  }
}

// Round 14
// 874.805 us; speedup vs baseline: 1.0132x; 1.0132x over previous
//
#include <hip/hip_runtime.h>
#include <cstdint>
#include <cstddef>

static constexpr int HD = 200;   // hidden
static constexpr int NH = 8;     // heads
static constexpr int CD = 25;    // per-head dim
static constexpr int NL = 4;     // layers

typedef unsigned int u32;
typedef unsigned int u32x4 __attribute__((ext_vector_type(4)));
typedef float f32x4 __attribute__((ext_vector_type(4)));
typedef __bf16 bf16x8 __attribute__((ext_vector_type(8)));

union U8cast { u32x4 u; bf16x8 b; };
__device__ inline bf16x8 as_bf16x8(u32x4 v) { U8cast x; x.u = v; return x.b; }

// truncation split: a = hi + lo + eps, |eps| <= 2^-16 |a|; packs 2 elems per u32.
__device__ inline void split2(float a0, float a1, u32& hi, u32& lo) {
  u32 u0 = __builtin_bit_cast(u32, a0), u1 = __builtin_bit_cast(u32, a1);
  u32 h0 = u0 & 0xffff0000u, h1 = u1 & 0xffff0000u;
  hi = (u0 >> 16) | h1;
  float r0 = a0 - __builtin_bit_cast(float, h0);
  float r1 = a1 - __builtin_bit_cast(float, h1);
  lo = (__builtin_bit_cast(u32, r0) >> 16) | (__builtin_bit_cast(u32, r1) & 0xffff0000u);
}

__device__ inline void mk_frags_r(f32x4 x0, f32x4 x1, bf16x8& hi8, bf16x8& lo8) {
  u32x4 h, l;
  u32 th, tl;
  split2(x0[0], x0[1], th, tl); h[0] = th; l[0] = tl;
  split2(x0[2], x0[3], th, tl); h[1] = th; l[1] = tl;
  split2(x1[0], x1[1], th, tl); h[2] = th; l[2] = tl;
  split2(x1[2], x1[3], th, tl); h[3] = th; l[3] = tl;
  hi8 = as_bf16x8(h); lo8 = as_bf16x8(l);
}

__device__ inline void mk_frags(const float* __restrict__ ap, bf16x8& hi8, bf16x8& lo8) {
  mk_frags_r(*(const f32x4*)ap, *(const f32x4*)(ap + 4), hi8, lo8);
}

// ---------------- CSR build ----------------
__global__ __launch_bounds__(256) void k_hist(const int* __restrict__ dst, int* __restrict__ cnt, int E) {
  int e = blockIdx.x * 256 + threadIdx.x;
  if (e < E) atomicAdd(&cnt[dst[e]], 1);
}

__global__ __launch_bounds__(256) void k_scan1(const int* __restrict__ cnt, int* __restrict__ off,
                                               int* __restrict__ partial, int N) {
  __shared__ int sm[256];
  int t = threadIdx.x, i = blockIdx.x * 256 + t;
  int v = (i < N) ? cnt[i] : 0;
  sm[t] = v; __syncthreads();
  for (int o = 1; o < 256; o <<= 1) {
    int add = (t >= o) ? sm[t - o] : 0;
    __syncthreads();
    sm[t] += add;
    __syncthreads();
  }
  if (i < N) off[i] = sm[t] - v;
  if (t == 255) partial[blockIdx.x] = sm[255];
}

__global__ __launch_bounds__(512) void k_scan2(int* __restrict__ partial, int nb, int* __restrict__ off, int N) {
  __shared__ int sm[512];
  int t = threadIdx.x;
  int v = (t < nb) ? partial[t] : 0;
  sm[t] = v; __syncthreads();
  for (int o = 1; o < 512; o <<= 1) {
    int add = (t >= o) ? sm[t - o] : 0;
    __syncthreads();
    sm[t] += add;
    __syncthreads();
  }
  if (t < nb) partial[t] = sm[t] - v;
  if (t == 511) off[N] = sm[511];
}

__global__ __launch_bounds__(256) void k_scan3(int* __restrict__ off, const int* __restrict__ partial, int N) {
  int i = blockIdx.x * 256 + threadIdx.x;
  if (i < N) off[i] += partial[i >> 8];
}

__global__ __launch_bounds__(256) void k_scatter(const int* __restrict__ dst, const int* __restrict__ off,
                                                 int* __restrict__ cur, int* __restrict__ eid, int E) {
  int e = blockIdx.x * 256 + threadIdx.x;
  if (e < E) {
    int d = dst[e];
    int p = atomicAdd(&cur[d], 1);
    eid[off[d] + p] = e;
  }
}

__global__ __launch_bounds__(256) void k_sort(const int* __restrict__ off, int* __restrict__ eid, int N) {
  int n = blockIdx.x * 256 + threadIdx.x;
  if (n >= N) return;
  int o0 = off[n], o1 = off[n + 1];
  for (int i = o0 + 1; i < o1; ++i) {
    int v = eid[i]; int j = i - 1;
    while (j >= o0 && eid[j] > v) { eid[j + 1] = eid[j]; --j; }
    eid[j + 1] = v;
  }
}

// ---------------- edge-attention precompute (algebraic reductions) ----------------
__global__ __launch_bounds__(128) void k_meanea(const float* __restrict__ ea, const int* __restrict__ off,
                                                const int* __restrict__ eid, float* __restrict__ mea, int N) {
  int n = blockIdx.x * 128 + threadIdx.x;
  if (n >= N) return;
  int o0 = off[n], o1 = off[n + 1];
  float s0 = 0, s1 = 0, s2 = 0, s3 = 0, s4 = 0, s5 = 0;
  for (int p = o0; p < o1; ++p) {
    const float* r = ea + (size_t)eid[p] * 6;
    s0 += r[0]; s1 += r[1]; s2 += r[2]; s3 += r[3]; s4 += r[4]; s5 += r[5];
  }
  float inv = (o1 > o0) ? 1.f / (float)(o1 - o0) : 0.f;
  float* m = mea + (size_t)n * 6;
  m[0] = s0 * inv; m[1] = s1 * inv; m[2] = s2 * inv; m[3] = s3 * inv; m[4] = s4 * inv; m[5] = s5 * inv;
}

// we[l][k][h]   = sum_c lin_edge_w[l][k][h*25+c] * att_edge[l][h][c]
// wsrc[l][k][h] = sum_c lin_w[l][k][h*25+c]      * att_src[l][h][c]
// wdst[l][k][h] = sum_c lin_w[l][k][h*25+c]      * att_dst[l][h][c]
__global__ __launch_bounds__(256) void k_we2(const float* __restrict__ lew, const float* __restrict__ linw,
                                             const float* __restrict__ aeg, const float* __restrict__ asg,
                                             const float* __restrict__ adg, float* __restrict__ we,
                                             float* __restrict__ wsrc, float* __restrict__ wdst) {
  int tid = blockIdx.x * 256 + threadIdx.x;
  if (tid >= NL * HD * 8) return;
  int l = tid / (HD * 8); int r = tid % (HD * 8); int k = r >> 3; int hh = r & 7;
  const float* We = lew + (size_t)l * HD * HD + (size_t)k * HD + hh * CD;
  const float* Wl = linw + (size_t)l * HD * HD + (size_t)k * HD + hh * CD;
  const float* ae = aeg + l * NH * CD + hh * CD;
  const float* as = asg + l * NH * CD + hh * CD;
  const float* ad = adg + l * NH * CD + hh * CD;
  float s0 = 0.f, s1 = 0.f, s2 = 0.f;
#pragma unroll
  for (int c = 0; c < CD; ++c) {
    float we_ = We[c], wl_ = Wl[c];
    s0 += we_ * ae[c]; s1 += wl_ * as[c]; s2 += wl_ * ad[c];
  }
  we[tid] = s0; wsrc[tid] = s1; wdst[tid] = s2;   // layout l*1600 + k*8 + h
}

// M[l][f][h] = sum_k edge_emb_w[f][k] * we[l][k][h];  cv[l][h] = sum_k edge_emb_b[k]*we[l][k][h]
__global__ __launch_bounds__(256) void k_M(const float* __restrict__ ew, const float* __restrict__ eb,
                                           const float* __restrict__ we, float* __restrict__ Mm,
                                           float* __restrict__ cv) {
  int tid = threadIdx.x;
  if (tid < NL * 6 * 8) {
    int l = tid / 48, r = tid % 48, f = r / 8, hh = r % 8;
    float s = 0.f;
    for (int k = 0; k < HD; ++k) s += ew[f * HD + k] * we[l * 1600 + k * 8 + hh];
    Mm[tid] = s;   // l*48 + f*8 + hh
  } else if (tid < NL * 6 * 8 + NL * 8) {
    int u = tid - NL * 6 * 8, l = u / 8, hh = u % 8;
    float s = 0.f;
    for (int k = 0; k < HD; ++k) s += eb[k] * we[l * 1600 + k * 8 + hh];
    cv[u] = s;
  }
}

// self-loop attention logit contribution ae_s for all layers
__global__ __launch_bounds__(256) void k_ae_self(const float* __restrict__ mea, const int* __restrict__ cnt,
                                                 const float* __restrict__ Mm, const float* __restrict__ cv,
                                                 float* __restrict__ aes, int N) {
  int n = blockIdx.x * 256 + threadIdx.x;
  if (n >= N) return;
  bool has = cnt[n] > 0;
  float v[6];
#pragma unroll
  for (int f = 0; f < 6; ++f) v[f] = mea[(size_t)n * 6 + f];
  for (int l = 0; l < NL; ++l)
#pragma unroll
    for (int hh = 0; hh < 8; ++hh) {
      float s = 0.f;
      if (has) {
        s = cv[l * 8 + hh];
#pragma unroll
        for (int f = 0; f < 6; ++f) s += v[f] * Mm[l * 48 + f * 8 + hh];
      }
      aes[(size_t)l * N * 8 + (size_t)n * 8 + hh] = s;
    }
}

// one-time: CSR-ordered src index + all-layer layer-invariant edge logit part
__global__ __launch_bounds__(256) void k_aep(const float* __restrict__ ea, const int* __restrict__ eid,
                                             const int* __restrict__ esrc, const float* __restrict__ Mm,
                                             const float* __restrict__ cv, int* __restrict__ src_csr,
                                             float* __restrict__ aep, int E) {
  int p = blockIdx.x * 256 + threadIdx.x;
  if (p >= E) return;
  int e = eid[p];
  src_csr[p] = esrc[e];
  float v[6];
  const float* er = ea + (size_t)e * 6;
#pragma unroll
  for (int f = 0; f < 6; ++f) v[f] = er[f];
#pragma unroll
  for (int l = 0; l < NL; ++l) {
#pragma unroll
    for (int hh = 0; hh < 8; ++hh) {
      float s = cv[l * 8 + hh];
#pragma unroll
      for (int f = 0; f < 6; ++f) s += v[f] * Mm[l * 48 + f * 8 + hh];
      aep[(size_t)l * E * 8 + (size_t)p * 8 + hh] = s;
    }
  }
}

// ---------------- weight split v5: LDS-image layout ----------------
__global__ __launch_bounds__(256) void k_split5(const float* __restrict__ W, u32* __restrict__ out,
                                                int K, int nsteps, int inStride,
                                                const float* __restrict__ wsrc,
                                                const float* __restrict__ wdst) {
  int l = blockIdx.y;
  int tot = nsteps * 7168;
  int idx = blockIdx.x * 256 + threadIdx.x;
  if (idx >= tot) return;
  int ks = idx / 7168, r = idx % 7168;
  int plane = r / 3584, r2 = r % 3584;
  int g = r2 >> 2, j = r2 & 3;
  int c = g >> 2, kg = g & 3;
  int k = ks * 32 + kg * 8 + j * 2;
  float a0 = 0.f, a1 = 0.f;
  if (c < HD) {
    if (k < K) {
      const float* Wl = W + (size_t)l * inStride;
      a0 = Wl[(size_t)k * HD + c];
      a1 = Wl[(size_t)(k + 1) * HD + c];
    }
  } else if (wsrc && c < 216 && k < K) {
    const float* src = ((c < 208) ? wsrc : wdst) + (size_t)l * 1600;
    int hh = (c - 200) & 7;
    a0 = src[k * 8 + hh];
    a1 = src[(k + 1) * 8 + hh];
  }
  u32 hi, lo; split2(a0, a1, hi, lo);
  out[(size_t)l * tot + idx] = (plane == 0) ? hi : lo;
}

// merged readout split: readout_w [4][200][200] -> LDS-image [25 ks][7168 u32], K global 0..799
__global__ __launch_bounds__(256) void k_split_ro5(const float* __restrict__ W, u32* __restrict__ out) {
  int idx = blockIdx.x * 256 + threadIdx.x;
  if (idx >= 25 * 7168) return;
  int ks = idx / 7168, r = idx % 7168;
  int plane = r / 3584, r2 = r % 3584;
  int g = r2 >> 2, j = r2 & 3;
  int c = g >> 2, kg = g & 3;
  int k = ks * 32 + kg * 8 + j * 2;
  float a0 = 0.f, a1 = 0.f;
  if (c < HD) {
    int lsrc = k / HD, kl = k % HD;
    const float* Wl = W + (size_t)lsrc * HD * HD;
    a0 = Wl[(size_t)kl * HD + c];
    a1 = Wl[(size_t)(kl + 1) * HD + c];
  }
  u32 hi, lo; split2(a0, a1, hi, lo);
  out[idx] = (plane == 0) ? hi : lo;
}

// summed readout bias
__global__ __launch_bounds__(256) void k_bsum(const float* __restrict__ rb, float* __restrict__ out) {
  int t = threadIdx.x;
  if (t < HD) out[t] = rb[t] + rb[HD + t] + rb[2 * HD + t] + rb[3 * HD + t];
}

// head W1 split: head_w1 [5][200][100] -> planes [t][112 cols][224 k] bf16
__global__ __launch_bounds__(256) void k_split_hw(const float* __restrict__ W, u32* __restrict__ hiT,
                                                  u32* __restrict__ loT) {
  int t = blockIdx.y;
  int idx = blockIdx.x * 256 + threadIdx.x;
  if (idx >= 112 * 112) return;
  int c = idx / 112, kp = (idx % 112) * 2;
  const float* Wt = W + (size_t)t * HD * 100;
  float a0 = (c < 100 && kp < HD) ? Wt[(size_t)kp * 100 + c] : 0.f;
  float a1 = (c < 100 && kp + 1 < HD) ? Wt[(size_t)(kp + 1) * 100 + c] : 0.f;
  u32 hi, lo; split2(a0, a1, hi, lo);
  size_t ob = (size_t)t * 112 * 112 + idx;
  hiT[ob] = hi; loT[ob] = lo;
}

// ---------------- MFMA GEMM v7: half-K-step LDS pipeline (28 KB -> 5 blocks/CU) ----------------
// Same math as v5 but each 28 KB K-step stage is split into its hi/lo planes (14 KB each):
// buf0 always holds hi planes, buf1 lo planes; stage next half while consuming current.
// Per-acc MFMA order becomes (ah*bh, al*bh, ah*bl) -- FP reorder of the same 3 terms.
template<int NSTEPS, bool ATTN>
__global__ __launch_bounds__(256) void k_gemm_v7(const float* __restrict__ A, const u32* __restrict__ Bpk,
                                                 const float* __restrict__ bias, float* __restrict__ C,
                                                 float* __restrict__ aS, float* __restrict__ aD,
                                                 int M, int K) {
  constexpr int NT = 7;
  constexpr int NHALF = NSTEPS * 2;
  __shared__ u32 smem[2 * 3584];            // 28672 B
  const int tid = threadIdx.x;
  const int lane = tid & 63;
  const int w = tid >> 6;
  const int wm = w >> 1, wn = w & 1;
  const int lr = lane & 15, kg = lane >> 4;
  const int kg8 = kg * 8;

  const int rowA0 = blockIdx.x * 64 + wm * 32 + lr;
  const int rowA1 = rowA0 + 16;
  const float* Ap0 = A + (size_t)((rowA0 < M) ? rowA0 : (M - 1)) * K;
  const float* Ap1 = A + (size_t)((rowA1 < M) ? rowA1 : (M - 1)) * K;
  const int colbase = wn * 112;
  const int dsbase = (colbase + lr) * 16 + kg * 4;   // u32 index within a plane

  f32x4 acc[2][NT];
#pragma unroll
  for (int mt = 0; mt < 2; ++mt)
#pragma unroll
    for (int t = 0; t < NT; ++t) acc[mt][t] = (f32x4)0.f;

  // stage half s (s>>1 = ks, s&1 = plane) into buf[s&1]; 14 chunks of 1 KB over 4 waves
  auto stage = [&](int s) {
    const u32* src = Bpk + (size_t)(s >> 1) * 7168 + (size_t)(s & 1) * 3584;
    u32* dst = smem + (s & 1) * 3584;
#pragma unroll
    for (int i = 0; i < 4; ++i) {
      const int chunk = i * 4 + w;
      if (chunk < 14)
        __builtin_amdgcn_global_load_lds((const void*)(src + chunk * 256 + lane * 4),
                                         (void*)(dst + chunk * 256), 16, 0, 0);
    }
  };

  // prologue: stage hi(ks=0); prefetch A(ks=0)
  stage(0);
  f32x4 a0c, a0d, a1c, a1d;
  a0c = *(const f32x4*)(Ap0 + kg8); a0d = *(const f32x4*)(Ap0 + kg8 + 4);
  a1c = *(const f32x4*)(Ap1 + kg8); a1d = *(const f32x4*)(Ap1 + kg8 + 4);
  __syncthreads();

  bf16x8 ah0, al0, ah1, al1;
  for (int ks = 0; ks < NSTEPS; ++ks) {
    // ---- phase HI: stage lo(ks); build A frags; consume hi plane (buf0) ----
    stage(2 * ks + 1);
    {
      const int k0 = ks * 32 + kg8;
      if (k0 < K) {
        mk_frags_r(a0c, a0d, ah0, al0);
        mk_frags_r(a1c, a1d, ah1, al1);
      } else {
        u32x4 zz; zz[0] = 0; zz[1] = 0; zz[2] = 0; zz[3] = 0;
        ah0 = as_bf16x8(zz); al0 = ah0; ah1 = ah0; al1 = ah0;
      }
    }
#pragma unroll
    for (int t = 0; t < NT; ++t) {
      bf16x8 bh = as_bf16x8(*(const u32x4*)(smem + dsbase + t * 256));
      acc[0][t] = __builtin_amdgcn_mfma_f32_16x16x32_bf16(ah0, bh, acc[0][t], 0, 0, 0);
      acc[0][t] = __builtin_amdgcn_mfma_f32_16x16x32_bf16(al0, bh, acc[0][t], 0, 0, 0);
      acc[1][t] = __builtin_amdgcn_mfma_f32_16x16x32_bf16(ah1, bh, acc[1][t], 0, 0, 0);
      acc[1][t] = __builtin_amdgcn_mfma_f32_16x16x32_bf16(al1, bh, acc[1][t], 0, 0, 0);
    }
    __syncthreads();
    // ---- phase LO: stage hi(ks+1); consume lo plane (buf1); prefetch A(ks+1) ----
    if (2 * ks + 2 < NHALF) stage(2 * ks + 2);
    if (ks + 1 < NSTEPS) {
      const int k0n = (ks + 1) * 32 + kg8;
      if (k0n < K) {
        a0c = *(const f32x4*)(Ap0 + k0n); a0d = *(const f32x4*)(Ap0 + k0n + 4);
        a1c = *(const f32x4*)(Ap1 + k0n); a1d = *(const f32x4*)(Ap1 + k0n + 4);
      }
    }
#pragma unroll
    for (int t = 0; t < NT; ++t) {
      bf16x8 bl = as_bf16x8(*(const u32x4*)(smem + 3584 + dsbase + t * 256));
      acc[0][t] = __builtin_amdgcn_mfma_f32_16x16x32_bf16(ah0, bl, acc[0][t], 0, 0, 0);
      acc[1][t] = __builtin_amdgcn_mfma_f32_16x16x32_bf16(ah1, bl, acc[1][t], 0, 0, 0);
    }
    __syncthreads();
  }

#pragma unroll
  for (int mt = 0; mt < 2; ++mt) {
    const int rbase = blockIdx.x * 64 + wm * 32 + mt * 16 + kg * 4;
#pragma unroll
    for (int t = 0; t < NT; ++t) {
      const int c = colbase + t * 16 + lr;
      if (c < HD) {
        const float badd = bias ? bias[c] : 0.f;
#pragma unroll
        for (int j = 0; j < 4; ++j) {
          const int r = rbase + j;
          if (r < M) C[(size_t)r * HD + c] = acc[mt][t][j] + badd;
        }
      } else if (ATTN && c < 216) {
        float* dstp = (c < 208) ? aS : aD;
        const int hh = (c - 200) & 7;
#pragma unroll
        for (int j = 0; j < 4; ++j) {
          const int r = rbase + j;
          if (r < M) dstp[(size_t)r * 8 + hh] = acc[mt][t][j];
        }
      }
    }
  }
}

// ---------------- head GEMM fused with w2 dot + sigmoid: out[t][g] directly ----------------
__global__ __launch_bounds__(128) void k_headgemm(const float* __restrict__ A, const u32* __restrict__ hwHi,
                                                  const u32* __restrict__ hwLo, const float* __restrict__ b1,
                                                  const float* __restrict__ w2, const float* __restrict__ b2,
                                                  float* __restrict__ out, int M) {
  const int task = blockIdx.y;
  const int lane = threadIdx.x & 63;
  const int w = threadIdx.x >> 6;
  const int lr = lane & 15, kg = lane >> 4;
  const int K = HD;
  const int nStep = 7;
  const int bstride = 112;

  const int rowA0 = blockIdx.x * 64 + w * 32 + lr;
  const int rowA1 = rowA0 + 16;
  const float* Ap0 = A + (size_t)((rowA0 < M) ? rowA0 : (M - 1)) * K;
  const float* Ap1 = A + (size_t)((rowA1 < M) ? rowA1 : (M - 1)) * K;
  const u32* BhT = hwHi + (size_t)task * 112 * 112;
  const u32* BlT = hwLo + (size_t)task * 112 * 112;

  f32x4 acc[2][7];
#pragma unroll
  for (int mt = 0; mt < 2; ++mt)
#pragma unroll
    for (int t = 0; t < 7; ++t) acc[mt][t] = (f32x4)0.f;

  u32x4 zz; zz[0] = 0; zz[1] = 0; zz[2] = 0; zz[3] = 0;
  const bf16x8 zfrag = as_bf16x8(zz);

  for (int ks = 0; ks < nStep; ++ks) {
    const int kb = ks * 32;
    const int k0 = kb + kg * 8;
    bf16x8 ah0, al0, ah1, al1;
    if (k0 < K) {
      mk_frags(Ap0 + k0, ah0, al0);
      mk_frags(Ap1 + k0, ah1, al1);
    } else {
      ah0 = zfrag; al0 = zfrag; ah1 = zfrag; al1 = zfrag;
    }
    const u32* Bh = BhT + (kb >> 1) + kg * 4;
    const u32* Bl = BlT + (kb >> 1) + kg * 4;
#pragma unroll
    for (int t = 0; t < 7; ++t) {
      const size_t cb = (size_t)(t * 16 + lr) * bstride;
      bf16x8 bh = as_bf16x8(*(const u32x4*)(Bh + cb));
      bf16x8 bl = as_bf16x8(*(const u32x4*)(Bl + cb));
      acc[0][t] = __builtin_amdgcn_mfma_f32_16x16x32_bf16(ah0, bh, acc[0][t], 0, 0, 0);
      acc[0][t] = __builtin_amdgcn_mfma_f32_16x16x32_bf16(ah0, bl, acc[0][t], 0, 0, 0);
      acc[0][t] = __builtin_amdgcn_mfma_f32_16x16x32_bf16(al0, bh, acc[0][t], 0, 0, 0);
      acc[1][t] = __builtin_amdgcn_mfma_f32_16x16x32_bf16(ah1, bh, acc[1][t], 0, 0, 0);
      acc[1][t] = __builtin_amdgcn_mfma_f32_16x16x32_bf16(ah1, bl, acc[1][t], 0, 0, 0);
      acc[1][t] = __builtin_amdgcn_mfma_f32_16x16x32_bf16(al1, bh, acc[1][t], 0, 0, 0);
    }
  }

  float w2v[7], b1v[7];
#pragma unroll
  for (int t = 0; t < 7; ++t) {
    const int c = t * 16 + lr;
    w2v[t] = (c < 100) ? w2[task * 100 + c] : 0.f;
    b1v[t] = (c < 100) ? b1[task * 100 + c] : 0.f;
  }
  const bool sig = (task == 0) | (task == 3) | (task == 4);
#pragma unroll
  for (int mt = 0; mt < 2; ++mt) {
    const int rbase = blockIdx.x * 64 + w * 32 + mt * 16 + kg * 4;
#pragma unroll
    for (int j = 0; j < 4; ++j) {
      float part = 0.f;
#pragma unroll
      for (int t = 0; t < 7; ++t) {
        const int c = t * 16 + lr;
        if (c < 100) {
          float v = acc[mt][t][j] + b1v[t];
          v = v > 0.f ? v : 0.f;
          part += v * w2v[t];
        }
      }
      part += __shfl_xor(part, 1);
      part += __shfl_xor(part, 2);
      part += __shfl_xor(part, 4);
      part += __shfl_xor(part, 8);
      const int r = rbase + j;
      if (lr == 0 && r < M) {
        float zv = part + b2[task];
        out[(size_t)task * M + r] = sig ? 1.f / (1.f + expf(-zv)) : zv;
      }
    }
  }
}

// ---------------- aggregation v4: block per graph, fused global_add_pool (R11 form) ----------------
__global__ __launch_bounds__(256) void k_aggr4(const float* __restrict__ xs, const float* __restrict__ a_src,
                                               const float* __restrict__ a_dst, const float* __restrict__ aep,
                                               const float* __restrict__ aes, const float* __restrict__ gb,
                                               const int* __restrict__ off, const int* __restrict__ src_csr,
                                               const int* __restrict__ gstart, float* __restrict__ h_out,
                                               float* __restrict__ pooled, int coff, int writeH) {
  __shared__ float red[4][HD];
  const int g = blockIdx.x;
  const int lane = threadIdx.x & 63;
  const int wv = threadIdx.x >> 6;
  const int s0g = gstart[g], s1g = gstart[g + 1];
  const int h = lane & 7, q = lane >> 3;
  const int c0 = lane * 4;                 // cols c0..c0+3 (lanes 0..49)
  const bool val4 = lane < 50;
  const int h0 = val4 ? (c0 / 25) : 0;
  const int h3 = val4 ? ((c0 + 3) / 25) : 0;
  const int bcut = 25 * (h0 + 1) - c0;     // #elems in head h0

  f32x4 pacc = (f32x4)0.f;

  for (int node = s0g + wv; node < s1g; node += 4) {
    const int o0 = off[node], o1 = off[node + 1];
    const float adst_h = a_dst[(size_t)node * 8 + h];
    float lself = 0.f;
    if (lane < 8) {
      float v = a_src[(size_t)node * 8 + lane] + a_dst[(size_t)node * 8 + lane]
              + aes[(size_t)node * 8 + lane];
      lself = (v >= 0.f) ? v : 0.2f * v;
    }
    // chunk 0 logits in registers (deg <= 8 fast path)
    const int p0i = o0 + q;
    const bool v0 = p0i < o1;
    int s0 = 0; float lg0 = -1e30f;
    if (v0) {
      s0 = src_csr[p0i];
      float av = a_src[(size_t)s0 * 8 + h] + adst_h + aep[(size_t)p0i * 8 + h];
      lg0 = (av >= 0.f) ? av : 0.2f * av;
    }
    float mx = lg0;
    for (int pb = o0 + 8; pb < o1; pb += 8) {
      int p = pb + q;
      if (p < o1) {
        int s = src_csr[p];
        float av = a_src[(size_t)s * 8 + h] + adst_h + aep[(size_t)p * 8 + h];
        av = (av >= 0.f) ? av : 0.2f * av;
        mx = fmaxf(mx, av);
      }
    }
    mx = fmaxf(mx, __shfl_xor(mx, 8));
    mx = fmaxf(mx, __shfl_xor(mx, 16));
    mx = fmaxf(mx, __shfl_xor(mx, 32));
    mx = fmaxf(mx, __shfl(lself, h));

    f32x4 acc = (f32x4)0.f;
    float wsum = 0.f;
    // chunk 0
    {
      float wgt = v0 ? expf(lg0 - mx) : 0.f;
      wsum += wgt;
      int cnt = o1 - o0; if (cnt > 8) cnt = 8;
      for (int j = 0; j < cnt; ++j) {
        float wA = __shfl(wgt, j * 8 + h0);
        float wB = __shfl(wgt, j * 8 + h3);
        int sj = __shfl(s0, j * 8);
        if (val4) {
          f32x4 xv = *(const f32x4*)(xs + (size_t)sj * HD + c0);
#pragma unroll
          for (int i = 0; i < 4; ++i)
            acc[i] += ((i < bcut) ? wA : wB) * xv[i];
        }
      }
    }
    // remaining chunks (deg > 8, rare)
    for (int pb = o0 + 8; pb < o1; pb += 8) {
      int p = pb + q;
      bool valid = p < o1;
      float wgt = 0.f; int s = 0;
      if (valid) {
        s = src_csr[p];
        float av = a_src[(size_t)s * 8 + h] + adst_h + aep[(size_t)p * 8 + h];
        av = (av >= 0.f) ? av : 0.2f * av;
        wgt = expf(av - mx);
      }
      wsum += wgt;
      int cnt = o1 - pb; if (cnt > 8) cnt = 8;
      for (int j = 0; j < cnt; ++j) {
        float wA = __shfl(wgt, j * 8 + h0);
        float wB = __shfl(wgt, j * 8 + h3);
        int sj = __shfl(s, j * 8);
        if (val4) {
          f32x4 xv = *(const f32x4*)(xs + (size_t)sj * HD + c0);
#pragma unroll
          for (int i = 0; i < 4; ++i)
            acc[i] += ((i < bcut) ? wA : wB) * xv[i];
        }
      }
    }
    wsum += __shfl_xor(wsum, 8);
    wsum += __shfl_xor(wsum, 16);
    wsum += __shfl_xor(wsum, 32);
    // self contribution last (reference concat order)
    float wself = (lane < 8) ? expf(lself - mx) : 0.f;
    {
      float wA = __shfl(wself, h0);
      float wB = __shfl(wself, h3);
      if (val4) {
        f32x4 xv = *(const f32x4*)(xs + (size_t)node * HD + c0);
#pragma unroll
        for (int i = 0; i < 4; ++i)
          acc[i] += ((i < bcut) ? wA : wB) * xv[i];
      }
      wsum += __shfl(wself, h);
    }
    float denA = __shfl(wsum, h0) + 1e-16f;
    float denB = __shfl(wsum, h3) + 1e-16f;
    if (val4) {
      f32x4 gv = *(const f32x4*)(gb + c0);
      f32x4 hv;
#pragma unroll
      for (int i = 0; i < 4; ++i)
        hv[i] = acc[i] / ((i < bcut) ? denA : denB) + gv[i];
      if (writeH) *(f32x4*)(h_out + (size_t)node * HD + c0) = hv;
      pacc += hv;
    }
  }
  // cross-wave pooled reduction -> pooled[g][coff + c]
  if (val4) *(f32x4*)(&red[wv][c0]) = pacc;
  __syncthreads();
  if (wv == 0 && val4) {
    f32x4 r0 = *(const f32x4*)(&red[0][c0]);
    f32x4 r1 = *(const f32x4*)(&red[1][c0]);
    f32x4 r2 = *(const f32x4*)(&red[2][c0]);
    f32x4 r3 = *(const f32x4*)(&red[3][c0]);
    f32x4 s = (r0 + r1) + (r2 + r3);
    *(f32x4*)(pooled + (size_t)g * 800 + coff + c0) = s;
  }
}

__global__ __launch_bounds__(256) void k_gstart(const int* __restrict__ batch, int* __restrict__ gstart,
                                                int N, int G) {
  int i = blockIdx.x * 256 + threadIdx.x;
  if (i >= N) return;
  int b = batch[i];
  int pb = (i == 0) ? -1 : batch[i - 1];
  for (int g = pb + 1; g <= b; ++g) gstart[g] = i;
  if (i == N - 1) for (int g = b + 1; g <= G; ++g) gstart[g] = N;
}

extern "C" void kernel_launch(void* const* d_in, const int* in_sizes, int n_in,
                              void* d_out, int out_size, void* d_ws, size_t ws_size,
                              hipStream_t stream) {
  const float* x         = (const float*)d_in[0];
  const float* edge_attr = (const float*)d_in[1];
  const float* node_w    = (const float*)d_in[2];
  const float* node_b    = (const float*)d_in[3];
  const float* edge_w    = (const float*)d_in[4];
  const float* edge_b    = (const float*)d_in[5];
  const float* lin_w     = (const float*)d_in[6];
  const float* lin_edge_w= (const float*)d_in[7];
  const float* att_src   = (const float*)d_in[8];
  const float* att_dst   = (const float*)d_in[9];
  const float* att_edge  = (const float*)d_in[10];
  const float* gat_bias  = (const float*)d_in[11];
  const float* readout_w = (const float*)d_in[12];
  const float* readout_b = (const float*)d_in[13];
  const float* head_w1   = (const float*)d_in[14];
  const float* head_b1   = (const float*)d_in[15];
  const float* head_w2   = (const float*)d_in[16];
  const float* head_b2   = (const float*)d_in[17];
  const int*   edge_index= (const int*)d_in[18];
  const int*   batch     = (const int*)d_in[19];

  const int N = in_sizes[0] / 64;
  const int E = in_sizes[1] / 6;
  const int G = out_size / 5;
  const int* srcI = edge_index;
  const int* dstI = edge_index + E;

  char* wsb = (char*)d_ws;
  size_t o = 0;
  auto alloc = [&](size_t bytes) -> void* {
    void* p = wsb + o;
    o = (o + bytes + 255) & ~(size_t)255;
    return p;
  };
  float* h       = (float*)alloc((size_t)N * HD * 4);
  float* xs      = (float*)alloc((size_t)N * HD * 4);
  float* a_src   = (float*)alloc((size_t)N * 8 * 4);
  float* a_dst   = (float*)alloc((size_t)N * 8 * 4);
  float* aep     = (float*)alloc((size_t)NL * E * 8 * 4);
  int*   src_csr = (int*)alloc((size_t)E * 4);
  float* ae_s    = (float*)alloc((size_t)NL * N * 8 * 4);
  float* mean_ea = (float*)alloc((size_t)N * 6 * 4);
  float* we      = (float*)alloc((size_t)NL * HD * 8 * 4);
  float* wsrc    = (float*)alloc((size_t)NL * HD * 8 * 4);
  float* wdst    = (float*)alloc((size_t)NL * HD * 8 * 4);
  float* Mm      = (float*)alloc((size_t)NL * 6 * 8 * 4);
  float* cv      = (float*)alloc((size_t)NL * 8 * 4);
  int* cnt       = (int*)alloc((size_t)N * 4);
  int* cur       = (int*)alloc((size_t)N * 4);
  int* off       = (int*)alloc((size_t)(N + 1) * 4);
  int* partial   = (int*)alloc(512 * 4);
  int* eid       = (int*)alloc((size_t)E * 4);
  int* gstart    = (int*)alloc((size_t)(G + 1) * 4);
  float* pooled4 = (float*)alloc((size_t)G * 800 * 4);
  float* readouts= (float*)alloc((size_t)G * HD * 4);
  float* bsum    = (float*)alloc(HD * 4);
  // pre-split LDS-image weight buffers (u32 = 2 bf16; 7168 u32 per K-step)
  u32* nodePk    = (u32*)alloc((size_t)2 * 7168 * 4);
  u32* linPk     = (u32*)alloc((size_t)NL * 7 * 7168 * 4);
  u32* roPk      = (u32*)alloc((size_t)25 * 7168 * 4);
  u32* hw_hi     = (u32*)alloc((size_t)5 * 112 * 112 * 4);
  u32* hw_lo     = (u32*)alloc((size_t)5 * 112 * 112 * 4);
  (void)ws_size; (void)n_in;

  hipMemsetAsync(cnt, 0, (size_t)N * 4, stream);
  hipMemsetAsync(cur, 0, (size_t)N * 4, stream);

  int nb = (N + 255) / 256;
  k_hist<<<(E + 255) / 256, 256, 0, stream>>>(dstI, cnt, E);
  k_scan1<<<nb, 256, 0, stream>>>(cnt, off, partial, N);
  k_scan2<<<1, 512, 0, stream>>>(partial, nb, off, N);
  k_scan3<<<nb, 256, 0, stream>>>(off, partial, N);
  k_scatter<<<(E + 255) / 256, 256, 0, stream>>>(dstI, off, cur, eid, E);
  k_sort<<<nb, 256, 0, stream>>>(off, eid, N);
  k_meanea<<<(N + 127) / 128, 128, 0, stream>>>(edge_attr, off, eid, mean_ea, N);
  k_we2<<<(NL * HD * 8 + 255) / 256, 256, 0, stream>>>(lin_edge_w, lin_w, att_edge, att_src, att_dst,
                                                       we, wsrc, wdst);
  k_M<<<1, 256, 0, stream>>>(edge_w, edge_b, we, Mm, cv);
  k_ae_self<<<(N + 255) / 256, 256, 0, stream>>>(mean_ea, cnt, Mm, cv, ae_s, N);
  k_aep<<<(E + 255) / 256, 256, 0, stream>>>(edge_attr, eid, srcI, Mm, cv, src_csr, aep, E);

  // weight splits
  {
    k_split5<<<dim3((2 * 7168 + 255) / 256, 1), 256, 0, stream>>>(node_w, nodePk, 64, 2, 0,
                                                                  nullptr, nullptr);
    k_split5<<<dim3((7 * 7168 + 255) / 256, NL), 256, 0, stream>>>(lin_w, linPk, HD, 7, HD * HD,
                                                                   wsrc, wdst);
    k_split_ro5<<<(25 * 7168 + 255) / 256, 256, 0, stream>>>(readout_w, roPk);
    k_bsum<<<1, 256, 0, stream>>>(readout_b, bsum);
    dim3 g3((112 * 112 + 255) / 256, 5);
    k_split_hw<<<g3, 256, 0, stream>>>(head_w1, hw_hi, hw_lo);
  }

  const int gemmBlocks = (N + 63) / 64;
  k_gemm_v7<2, false><<<gemmBlocks, 256, 0, stream>>>(x, nodePk, node_b, h, nullptr, nullptr, N, 64);
  k_gstart<<<nb, 256, 0, stream>>>(batch, gstart, N, G);

  for (int l = 0; l < NL; ++l) {
    k_gemm_v7<7, true><<<gemmBlocks, 256, 0, stream>>>(h, linPk + (size_t)l * 7 * 7168,
                                                       nullptr, xs, a_src, a_dst, N, HD);
    k_aggr4<<<G, 256, 0, stream>>>(xs, a_src, a_dst, aep + (size_t)l * E * 8,
                                   ae_s + (size_t)l * N * 8, gat_bias + l * HD,
                                   off, src_csr, gstart, h, pooled4, l * HD, (l < NL - 1) ? 1 : 0);
  }
  // merged readout: readouts = pooled4 @ roW4 + sum_l b_l   (K = 800)
  k_gemm_v7<25, false><<<(G + 63) / 64, 256, 0, stream>>>(pooled4, roPk, bsum, readouts,
                                                          nullptr, nullptr, G, 800);
  {
    dim3 hg((G + 63) / 64, 5);
    k_headgemm<<<hg, 128, 0, stream>>>(readouts, hw_hi, hw_lo, head_b1, head_w2, head_b2,
                                       (float*)d_out, G);
  }
}

// Round 15
// 837.594 us; speedup vs baseline: 1.0582x; 1.0444x over previous
//
#include <hip/hip_runtime.h>
#include <cstdint>
#include <cstddef>

static constexpr int HD = 200;   // hidden
static constexpr int NH = 8;     // heads
static constexpr int CD = 25;    // per-head dim
static constexpr int NL = 4;     // layers

typedef unsigned int u32;
typedef unsigned int u32x4 __attribute__((ext_vector_type(4)));
typedef float f32x4 __attribute__((ext_vector_type(4)));
typedef __bf16 bf16x8 __attribute__((ext_vector_type(8)));

union U8cast { u32x4 u; bf16x8 b; };
__device__ inline bf16x8 as_bf16x8(u32x4 v) { U8cast x; x.u = v; return x.b; }

// truncation split: a = hi + lo + eps, |eps| <= 2^-16 |a|; packs 2 elems per u32.
__device__ inline void split2(float a0, float a1, u32& hi, u32& lo) {
  u32 u0 = __builtin_bit_cast(u32, a0), u1 = __builtin_bit_cast(u32, a1);
  u32 h0 = u0 & 0xffff0000u, h1 = u1 & 0xffff0000u;
  hi = (u0 >> 16) | h1;
  float r0 = a0 - __builtin_bit_cast(float, h0);
  float r1 = a1 - __builtin_bit_cast(float, h1);
  lo = (__builtin_bit_cast(u32, r0) >> 16) | (__builtin_bit_cast(u32, r1) & 0xffff0000u);
}

__device__ inline void mk_frags_r(f32x4 x0, f32x4 x1, bf16x8& hi8, bf16x8& lo8) {
  u32x4 h, l;
  u32 th, tl;
  split2(x0[0], x0[1], th, tl); h[0] = th; l[0] = tl;
  split2(x0[2], x0[3], th, tl); h[1] = th; l[1] = tl;
  split2(x1[0], x1[1], th, tl); h[2] = th; l[2] = tl;
  split2(x1[2], x1[3], th, tl); h[3] = th; l[3] = tl;
  hi8 = as_bf16x8(h); lo8 = as_bf16x8(l);
}

__device__ inline void mk_frags(const float* __restrict__ ap, bf16x8& hi8, bf16x8& lo8) {
  mk_frags_r(*(const f32x4*)ap, *(const f32x4*)(ap + 4), hi8, lo8);
}

// ---------------- CSR build ----------------
__global__ __launch_bounds__(256) void k_hist(const int* __restrict__ dst, int* __restrict__ cnt, int E) {
  int e = blockIdx.x * 256 + threadIdx.x;
  if (e < E) atomicAdd(&cnt[dst[e]], 1);
}

__global__ __launch_bounds__(256) void k_scan1(const int* __restrict__ cnt, int* __restrict__ off,
                                               int* __restrict__ partial, int N) {
  __shared__ int sm[256];
  int t = threadIdx.x, i = blockIdx.x * 256 + t;
  int v = (i < N) ? cnt[i] : 0;
  sm[t] = v; __syncthreads();
  for (int o = 1; o < 256; o <<= 1) {
    int add = (t >= o) ? sm[t - o] : 0;
    __syncthreads();
    sm[t] += add;
    __syncthreads();
  }
  if (i < N) off[i] = sm[t] - v;
  if (t == 255) partial[blockIdx.x] = sm[255];
}

__global__ __launch_bounds__(512) void k_scan2(int* __restrict__ partial, int nb, int* __restrict__ off, int N) {
  __shared__ int sm[512];
  int t = threadIdx.x;
  int v = (t < nb) ? partial[t] : 0;
  sm[t] = v; __syncthreads();
  for (int o = 1; o < 512; o <<= 1) {
    int add = (t >= o) ? sm[t - o] : 0;
    __syncthreads();
    sm[t] += add;
    __syncthreads();
  }
  if (t < nb) partial[t] = sm[t] - v;
  if (t == 511) off[N] = sm[511];
}

__global__ __launch_bounds__(256) void k_scan3(int* __restrict__ off, const int* __restrict__ partial, int N) {
  int i = blockIdx.x * 256 + threadIdx.x;
  if (i < N) off[i] += partial[i >> 8];
}

__global__ __launch_bounds__(256) void k_scatter(const int* __restrict__ dst, const int* __restrict__ off,
                                                 int* __restrict__ cur, int* __restrict__ eid, int E) {
  int e = blockIdx.x * 256 + threadIdx.x;
  if (e < E) {
    int d = dst[e];
    int p = atomicAdd(&cur[d], 1);
    eid[off[d] + p] = e;
  }
}

__global__ __launch_bounds__(256) void k_sort(const int* __restrict__ off, int* __restrict__ eid, int N) {
  int n = blockIdx.x * 256 + threadIdx.x;
  if (n >= N) return;
  int o0 = off[n], o1 = off[n + 1];
  for (int i = o0 + 1; i < o1; ++i) {
    int v = eid[i]; int j = i - 1;
    while (j >= o0 && eid[j] > v) { eid[j + 1] = eid[j]; --j; }
    eid[j + 1] = v;
  }
}

// ---------------- edge-attention precompute (algebraic reductions) ----------------
__global__ __launch_bounds__(128) void k_meanea(const float* __restrict__ ea, const int* __restrict__ off,
                                                const int* __restrict__ eid, float* __restrict__ mea, int N) {
  int n = blockIdx.x * 128 + threadIdx.x;
  if (n >= N) return;
  int o0 = off[n], o1 = off[n + 1];
  float s0 = 0, s1 = 0, s2 = 0, s3 = 0, s4 = 0, s5 = 0;
  for (int p = o0; p < o1; ++p) {
    const float* r = ea + (size_t)eid[p] * 6;
    s0 += r[0]; s1 += r[1]; s2 += r[2]; s3 += r[3]; s4 += r[4]; s5 += r[5];
  }
  float inv = (o1 > o0) ? 1.f / (float)(o1 - o0) : 0.f;
  float* m = mea + (size_t)n * 6;
  m[0] = s0 * inv; m[1] = s1 * inv; m[2] = s2 * inv; m[3] = s3 * inv; m[4] = s4 * inv; m[5] = s5 * inv;
}

// we[l][k][h]   = sum_c lin_edge_w[l][k][h*25+c] * att_edge[l][h][c]
// wsrc[l][k][h] = sum_c lin_w[l][k][h*25+c]      * att_src[l][h][c]
// wdst[l][k][h] = sum_c lin_w[l][k][h*25+c]      * att_dst[l][h][c]
__global__ __launch_bounds__(256) void k_we2(const float* __restrict__ lew, const float* __restrict__ linw,
                                             const float* __restrict__ aeg, const float* __restrict__ asg,
                                             const float* __restrict__ adg, float* __restrict__ we,
                                             float* __restrict__ wsrc, float* __restrict__ wdst) {
  int tid = blockIdx.x * 256 + threadIdx.x;
  if (tid >= NL * HD * 8) return;
  int l = tid / (HD * 8); int r = tid % (HD * 8); int k = r >> 3; int hh = r & 7;
  const float* We = lew + (size_t)l * HD * HD + (size_t)k * HD + hh * CD;
  const float* Wl = linw + (size_t)l * HD * HD + (size_t)k * HD + hh * CD;
  const float* ae = aeg + l * NH * CD + hh * CD;
  const float* as = asg + l * NH * CD + hh * CD;
  const float* ad = adg + l * NH * CD + hh * CD;
  float s0 = 0.f, s1 = 0.f, s2 = 0.f;
#pragma unroll
  for (int c = 0; c < CD; ++c) {
    float we_ = We[c], wl_ = Wl[c];
    s0 += we_ * ae[c]; s1 += wl_ * as[c]; s2 += wl_ * ad[c];
  }
  we[tid] = s0; wsrc[tid] = s1; wdst[tid] = s2;   // layout l*1600 + k*8 + h
}

// M[l][f][h] = sum_k edge_emb_w[f][k] * we[l][k][h];  cv[l][h] = sum_k edge_emb_b[k]*we[l][k][h]
__global__ __launch_bounds__(256) void k_M(const float* __restrict__ ew, const float* __restrict__ eb,
                                           const float* __restrict__ we, float* __restrict__ Mm,
                                           float* __restrict__ cv) {
  int tid = threadIdx.x;
  if (tid < NL * 6 * 8) {
    int l = tid / 48, r = tid % 48, f = r / 8, hh = r % 8;
    float s = 0.f;
    for (int k = 0; k < HD; ++k) s += ew[f * HD + k] * we[l * 1600 + k * 8 + hh];
    Mm[tid] = s;   // l*48 + f*8 + hh
  } else if (tid < NL * 6 * 8 + NL * 8) {
    int u = tid - NL * 6 * 8, l = u / 8, hh = u % 8;
    float s = 0.f;
    for (int k = 0; k < HD; ++k) s += eb[k] * we[l * 1600 + k * 8 + hh];
    cv[u] = s;
  }
}

// self-loop attention logit contribution ae_s for all layers
__global__ __launch_bounds__(256) void k_ae_self(const float* __restrict__ mea, const int* __restrict__ cnt,
                                                 const float* __restrict__ Mm, const float* __restrict__ cv,
                                                 float* __restrict__ aes, int N) {
  int n = blockIdx.x * 256 + threadIdx.x;
  if (n >= N) return;
  bool has = cnt[n] > 0;
  float v[6];
#pragma unroll
  for (int f = 0; f < 6; ++f) v[f] = mea[(size_t)n * 6 + f];
  for (int l = 0; l < NL; ++l)
#pragma unroll
    for (int hh = 0; hh < 8; ++hh) {
      float s = 0.f;
      if (has) {
        s = cv[l * 8 + hh];
#pragma unroll
        for (int f = 0; f < 6; ++f) s += v[f] * Mm[l * 48 + f * 8 + hh];
      }
      aes[(size_t)l * N * 8 + (size_t)n * 8 + hh] = s;
    }
}

// one-time: CSR-ordered src index + all-layer layer-invariant edge logit part
__global__ __launch_bounds__(256) void k_aep(const float* __restrict__ ea, const int* __restrict__ eid,
                                             const int* __restrict__ esrc, const float* __restrict__ Mm,
                                             const float* __restrict__ cv, int* __restrict__ src_csr,
                                             float* __restrict__ aep, int E) {
  int p = blockIdx.x * 256 + threadIdx.x;
  if (p >= E) return;
  int e = eid[p];
  src_csr[p] = esrc[e];
  float v[6];
  const float* er = ea + (size_t)e * 6;
#pragma unroll
  for (int f = 0; f < 6; ++f) v[f] = er[f];
#pragma unroll
  for (int l = 0; l < NL; ++l) {
#pragma unroll
    for (int hh = 0; hh < 8; ++hh) {
      float s = cv[l * 8 + hh];
#pragma unroll
      for (int f = 0; f < 6; ++f) s += v[f] * Mm[l * 48 + f * 8 + hh];
      aep[(size_t)l * E * 8 + (size_t)p * 8 + hh] = s;
    }
  }
}

// ---------------- weight split v5: LDS-image layout ----------------
__global__ __launch_bounds__(256) void k_split5(const float* __restrict__ W, u32* __restrict__ out,
                                                int K, int nsteps, int inStride,
                                                const float* __restrict__ wsrc,
                                                const float* __restrict__ wdst) {
  int l = blockIdx.y;
  int tot = nsteps * 7168;
  int idx = blockIdx.x * 256 + threadIdx.x;
  if (idx >= tot) return;
  int ks = idx / 7168, r = idx % 7168;
  int plane = r / 3584, r2 = r % 3584;
  int g = r2 >> 2, j = r2 & 3;
  int c = g >> 2, kg = g & 3;
  int k = ks * 32 + kg * 8 + j * 2;
  float a0 = 0.f, a1 = 0.f;
  if (c < HD) {
    if (k < K) {
      const float* Wl = W + (size_t)l * inStride;
      a0 = Wl[(size_t)k * HD + c];
      a1 = Wl[(size_t)(k + 1) * HD + c];
    }
  } else if (wsrc && c < 216 && k < K) {
    const float* src = ((c < 208) ? wsrc : wdst) + (size_t)l * 1600;
    int hh = (c - 200) & 7;
    a0 = src[k * 8 + hh];
    a1 = src[(k + 1) * 8 + hh];
  }
  u32 hi, lo; split2(a0, a1, hi, lo);
  out[(size_t)l * tot + idx] = (plane == 0) ? hi : lo;
}

// merged readout split: readout_w [4][200][200] -> LDS-image [25 ks][7168 u32], K global 0..799
__global__ __launch_bounds__(256) void k_split_ro5(const float* __restrict__ W, u32* __restrict__ out) {
  int idx = blockIdx.x * 256 + threadIdx.x;
  if (idx >= 25 * 7168) return;
  int ks = idx / 7168, r = idx % 7168;
  int plane = r / 3584, r2 = r % 3584;
  int g = r2 >> 2, j = r2 & 3;
  int c = g >> 2, kg = g & 3;
  int k = ks * 32 + kg * 8 + j * 2;
  float a0 = 0.f, a1 = 0.f;
  if (c < HD) {
    int lsrc = k / HD, kl = k % HD;
    const float* Wl = W + (size_t)lsrc * HD * HD;
    a0 = Wl[(size_t)kl * HD + c];
    a1 = Wl[(size_t)(kl + 1) * HD + c];
  }
  u32 hi, lo; split2(a0, a1, hi, lo);
  out[idx] = (plane == 0) ? hi : lo;
}

// summed readout bias
__global__ __launch_bounds__(256) void k_bsum(const float* __restrict__ rb, float* __restrict__ out) {
  int t = threadIdx.x;
  if (t < HD) out[t] = rb[t] + rb[HD + t] + rb[2 * HD + t] + rb[3 * HD + t];
}

// head W1 split: head_w1 [5][200][100] -> planes [t][112 cols][224 k] bf16
__global__ __launch_bounds__(256) void k_split_hw(const float* __restrict__ W, u32* __restrict__ hiT,
                                                  u32* __restrict__ loT) {
  int t = blockIdx.y;
  int idx = blockIdx.x * 256 + threadIdx.x;
  if (idx >= 112 * 112) return;
  int c = idx / 112, kp = (idx % 112) * 2;
  const float* Wt = W + (size_t)t * HD * 100;
  float a0 = (c < 100 && kp < HD) ? Wt[(size_t)kp * 100 + c] : 0.f;
  float a1 = (c < 100 && kp + 1 < HD) ? Wt[(size_t)(kp + 1) * 100 + c] : 0.f;
  u32 hi, lo; split2(a0, a1, hi, lo);
  size_t ob = (size_t)t * 112 * 112 + idx;
  hiT[ob] = hi; loT[ob] = lo;
}

// ---------------- MFMA GEMM v5 (split-bf16, B double-buffered in LDS via global_load_lds) ----
template<int NSTEPS, bool ATTN>
__global__ __launch_bounds__(256) void k_gemm_v5(const float* __restrict__ A, const u32* __restrict__ Bpk,
                                                 const float* __restrict__ bias, float* __restrict__ C,
                                                 float* __restrict__ aS, float* __restrict__ aD,
                                                 int M, int K) {
  constexpr int NT = 7;
  __shared__ u32 smem[2 * 7168];
  const int tid = threadIdx.x;
  const int lane = tid & 63;
  const int w = tid >> 6;
  const int wm = w >> 1, wn = w & 1;
  const int lr = lane & 15, kg = lane >> 4;
  const int kg8 = kg * 8;

  const int rowA0 = blockIdx.x * 64 + wm * 32 + lr;
  const int rowA1 = rowA0 + 16;
  const float* Ap0 = A + (size_t)((rowA0 < M) ? rowA0 : (M - 1)) * K;
  const float* Ap1 = A + (size_t)((rowA1 < M) ? rowA1 : (M - 1)) * K;
  const int colbase = wn * 112;
  const int dsbase = (colbase + lr) * 16 + kg * 4;

  f32x4 acc[2][NT];
#pragma unroll
  for (int mt = 0; mt < 2; ++mt)
#pragma unroll
    for (int t = 0; t < NT; ++t) acc[mt][t] = (f32x4)0.f;

#pragma unroll
  for (int i = 0; i < 7; ++i) {
    const int chunk = i * 4 + w;
    __builtin_amdgcn_global_load_lds((const void*)(Bpk + chunk * 256 + lane * 4),
                                     (void*)(smem + chunk * 256), 16, 0, 0);
  }
  f32x4 a0c, a0d, a1c, a1d;
  a0c = *(const f32x4*)(Ap0 + kg8); a0d = *(const f32x4*)(Ap0 + kg8 + 4);
  a1c = *(const f32x4*)(Ap1 + kg8); a1d = *(const f32x4*)(Ap1 + kg8 + 4);
  __syncthreads();

  int cur = 0;
  for (int ks = 0; ks < NSTEPS; ++ks) {
    const bool more = (ks + 1) < NSTEPS;
    if (more) {
      const u32* src = Bpk + (size_t)(ks + 1) * 7168;
      u32* dst = smem + (cur ^ 1) * 7168;
#pragma unroll
      for (int i = 0; i < 7; ++i) {
        const int chunk = i * 4 + w;
        __builtin_amdgcn_global_load_lds((const void*)(src + chunk * 256 + lane * 4),
                                         (void*)(dst + chunk * 256), 16, 0, 0);
      }
    }
    bf16x8 ah0, al0, ah1, al1;
    {
      const int k0 = ks * 32 + kg8;
      if (k0 < K) {
        mk_frags_r(a0c, a0d, ah0, al0);
        mk_frags_r(a1c, a1d, ah1, al1);
      } else {
        u32x4 zz; zz[0] = 0; zz[1] = 0; zz[2] = 0; zz[3] = 0;
        ah0 = as_bf16x8(zz); al0 = ah0; ah1 = ah0; al1 = ah0;
      }
    }
    if (more) {
      const int k0n = (ks + 1) * 32 + kg8;
      if (k0n < K) {
        a0c = *(const f32x4*)(Ap0 + k0n); a0d = *(const f32x4*)(Ap0 + k0n + 4);
        a1c = *(const f32x4*)(Ap1 + k0n); a1d = *(const f32x4*)(Ap1 + k0n + 4);
      }
    }
    const u32* bb = smem + cur * 7168;
#pragma unroll
    for (int t = 0; t < NT; ++t) {
      bf16x8 bh = as_bf16x8(*(const u32x4*)(bb + dsbase + t * 256));
      bf16x8 bl = as_bf16x8(*(const u32x4*)(bb + 3584 + dsbase + t * 256));
      acc[0][t] = __builtin_amdgcn_mfma_f32_16x16x32_bf16(ah0, bh, acc[0][t], 0, 0, 0);
      acc[0][t] = __builtin_amdgcn_mfma_f32_16x16x32_bf16(ah0, bl, acc[0][t], 0, 0, 0);
      acc[0][t] = __builtin_amdgcn_mfma_f32_16x16x32_bf16(al0, bh, acc[0][t], 0, 0, 0);
      acc[1][t] = __builtin_amdgcn_mfma_f32_16x16x32_bf16(ah1, bh, acc[1][t], 0, 0, 0);
      acc[1][t] = __builtin_amdgcn_mfma_f32_16x16x32_bf16(ah1, bl, acc[1][t], 0, 0, 0);
      acc[1][t] = __builtin_amdgcn_mfma_f32_16x16x32_bf16(al1, bh, acc[1][t], 0, 0, 0);
    }
    __syncthreads();
    cur ^= 1;
  }

#pragma unroll
  for (int mt = 0; mt < 2; ++mt) {
    const int rbase = blockIdx.x * 64 + wm * 32 + mt * 16 + kg * 4;
#pragma unroll
    for (int t = 0; t < NT; ++t) {
      const int c = colbase + t * 16 + lr;
      if (c < HD) {
        const float badd = bias ? bias[c] : 0.f;
#pragma unroll
        for (int j = 0; j < 4; ++j) {
          const int r = rbase + j;
          if (r < M) C[(size_t)r * HD + c] = acc[mt][t][j] + badd;
        }
      } else if (ATTN && c < 216) {
        float* dstp = (c < 208) ? aS : aD;
        const int hh = (c - 200) & 7;
#pragma unroll
        for (int j = 0; j < 4; ++j) {
          const int r = rbase + j;
          if (r < M) dstp[(size_t)r * 8 + hh] = acc[mt][t][j];
        }
      }
    }
  }
}

// ---------------- head GEMM fused with w2 dot + sigmoid: out[t][g] directly ----------------
__global__ __launch_bounds__(128) void k_headgemm(const float* __restrict__ A, const u32* __restrict__ hwHi,
                                                  const u32* __restrict__ hwLo, const float* __restrict__ b1,
                                                  const float* __restrict__ w2, const float* __restrict__ b2,
                                                  float* __restrict__ out, int M) {
  const int task = blockIdx.y;
  const int lane = threadIdx.x & 63;
  const int w = threadIdx.x >> 6;
  const int lr = lane & 15, kg = lane >> 4;
  const int K = HD;
  const int nStep = 7;
  const int bstride = 112;

  const int rowA0 = blockIdx.x * 64 + w * 32 + lr;
  const int rowA1 = rowA0 + 16;
  const float* Ap0 = A + (size_t)((rowA0 < M) ? rowA0 : (M - 1)) * K;
  const float* Ap1 = A + (size_t)((rowA1 < M) ? rowA1 : (M - 1)) * K;
  const u32* BhT = hwHi + (size_t)task * 112 * 112;
  const u32* BlT = hwLo + (size_t)task * 112 * 112;

  f32x4 acc[2][7];
#pragma unroll
  for (int mt = 0; mt < 2; ++mt)
#pragma unroll
    for (int t = 0; t < 7; ++t) acc[mt][t] = (f32x4)0.f;

  u32x4 zz; zz[0] = 0; zz[1] = 0; zz[2] = 0; zz[3] = 0;
  const bf16x8 zfrag = as_bf16x8(zz);

  for (int ks = 0; ks < nStep; ++ks) {
    const int kb = ks * 32;
    const int k0 = kb + kg * 8;
    bf16x8 ah0, al0, ah1, al1;
    if (k0 < K) {
      mk_frags(Ap0 + k0, ah0, al0);
      mk_frags(Ap1 + k0, ah1, al1);
    } else {
      ah0 = zfrag; al0 = zfrag; ah1 = zfrag; al1 = zfrag;
    }
    const u32* Bh = BhT + (kb >> 1) + kg * 4;
    const u32* Bl = BlT + (kb >> 1) + kg * 4;
#pragma unroll
    for (int t = 0; t < 7; ++t) {
      const size_t cb = (size_t)(t * 16 + lr) * bstride;
      bf16x8 bh = as_bf16x8(*(const u32x4*)(Bh + cb));
      bf16x8 bl = as_bf16x8(*(const u32x4*)(Bl + cb));
      acc[0][t] = __builtin_amdgcn_mfma_f32_16x16x32_bf16(ah0, bh, acc[0][t], 0, 0, 0);
      acc[0][t] = __builtin_amdgcn_mfma_f32_16x16x32_bf16(ah0, bl, acc[0][t], 0, 0, 0);
      acc[0][t] = __builtin_amdgcn_mfma_f32_16x16x32_bf16(al0, bh, acc[0][t], 0, 0, 0);
      acc[1][t] = __builtin_amdgcn_mfma_f32_16x16x32_bf16(ah1, bh, acc[1][t], 0, 0, 0);
      acc[1][t] = __builtin_amdgcn_mfma_f32_16x16x32_bf16(ah1, bl, acc[1][t], 0, 0, 0);
      acc[1][t] = __builtin_amdgcn_mfma_f32_16x16x32_bf16(al1, bh, acc[1][t], 0, 0, 0);
    }
  }

  float w2v[7], b1v[7];
#pragma unroll
  for (int t = 0; t < 7; ++t) {
    const int c = t * 16 + lr;
    w2v[t] = (c < 100) ? w2[task * 100 + c] : 0.f;
    b1v[t] = (c < 100) ? b1[task * 100 + c] : 0.f;
  }
  const bool sig = (task == 0) | (task == 3) | (task == 4);
#pragma unroll
  for (int mt = 0; mt < 2; ++mt) {
    const int rbase = blockIdx.x * 64 + w * 32 + mt * 16 + kg * 4;
#pragma unroll
    for (int j = 0; j < 4; ++j) {
      float part = 0.f;
#pragma unroll
      for (int t = 0; t < 7; ++t) {
        const int c = t * 16 + lr;
        if (c < 100) {
          float v = acc[mt][t][j] + b1v[t];
          v = v > 0.f ? v : 0.f;
          part += v * w2v[t];
        }
      }
      part += __shfl_xor(part, 1);
      part += __shfl_xor(part, 2);
      part += __shfl_xor(part, 4);
      part += __shfl_xor(part, 8);
      const int r = rbase + j;
      if (lr == 0 && r < M) {
        float zv = part + b2[task];
        out[(size_t)task * M + r] = sig ? 1.f / (1.f + expf(-zv)) : zv;
      }
    }
  }
}

// ---------------- aggregation v4: block per graph, fused global_add_pool ----------------
__global__ __launch_bounds__(256) void k_aggr4(const float* __restrict__ xs, const float* __restrict__ a_src,
                                               const float* __restrict__ a_dst, const float* __restrict__ aep,
                                               const float* __restrict__ aes, const float* __restrict__ gb,
                                               const int* __restrict__ off, const int* __restrict__ src_csr,
                                               const int* __restrict__ gstart, float* __restrict__ h_out,
                                               float* __restrict__ pooled, int coff, int writeH) {
  __shared__ float red[4][HD];
  const int g = blockIdx.x;
  const int lane = threadIdx.x & 63;
  const int wv = threadIdx.x >> 6;
  const int s0g = gstart[g], s1g = gstart[g + 1];
  const int h = lane & 7, q = lane >> 3;
  const int c0 = lane * 4;                 // cols c0..c0+3 (lanes 0..49)
  const bool val4 = lane < 50;
  const int h0 = val4 ? (c0 / 25) : 0;
  const int h3 = val4 ? ((c0 + 3) / 25) : 0;
  const int bcut = 25 * (h0 + 1) - c0;     // #elems in head h0

  f32x4 pacc = (f32x4)0.f;

  for (int node = s0g + wv; node < s1g; node += 4) {
    const int o0 = off[node], o1 = off[node + 1];
    const float adst_h = a_dst[(size_t)node * 8 + h];
    float lself = 0.f;
    if (lane < 8) {
      float v = a_src[(size_t)node * 8 + lane] + a_dst[(size_t)node * 8 + lane]
              + aes[(size_t)node * 8 + lane];
      lself = (v >= 0.f) ? v : 0.2f * v;
    }
    // chunk 0 logits in registers (deg <= 8 fast path)
    const int p0i = o0 + q;
    const bool v0 = p0i < o1;
    int s0 = 0; float lg0 = -1e30f;
    if (v0) {
      s0 = src_csr[p0i];
      float av = a_src[(size_t)s0 * 8 + h] + adst_h + aep[(size_t)p0i * 8 + h];
      lg0 = (av >= 0.f) ? av : 0.2f * av;
    }
    float mx = lg0;
    for (int pb = o0 + 8; pb < o1; pb += 8) {
      int p = pb + q;
      if (p < o1) {
        int s = src_csr[p];
        float av = a_src[(size_t)s * 8 + h] + adst_h + aep[(size_t)p * 8 + h];
        av = (av >= 0.f) ? av : 0.2f * av;
        mx = fmaxf(mx, av);
      }
    }
    mx = fmaxf(mx, __shfl_xor(mx, 8));
    mx = fmaxf(mx, __shfl_xor(mx, 16));
    mx = fmaxf(mx, __shfl_xor(mx, 32));
    mx = fmaxf(mx, __shfl(lself, h));

    f32x4 acc = (f32x4)0.f;
    float wsum = 0.f;
    // chunk 0
    {
      float wgt = v0 ? expf(lg0 - mx) : 0.f;
      wsum += wgt;
      int cnt = o1 - o0; if (cnt > 8) cnt = 8;
      for (int j = 0; j < cnt; ++j) {
        float wA = __shfl(wgt, j * 8 + h0);
        float wB = __shfl(wgt, j * 8 + h3);
        int sj = __shfl(s0, j * 8);
        if (val4) {
          f32x4 xv = *(const f32x4*)(xs + (size_t)sj * HD + c0);
#pragma unroll
          for (int i = 0; i < 4; ++i)
            acc[i] += ((i < bcut) ? wA : wB) * xv[i];
        }
      }
    }
    // remaining chunks (deg > 8, rare)
    for (int pb = o0 + 8; pb < o1; pb += 8) {
      int p = pb + q;
      bool valid = p < o1;
      float wgt = 0.f; int s = 0;
      if (valid) {
        s = src_csr[p];
        float av = a_src[(size_t)s * 8 + h] + adst_h + aep[(size_t)p * 8 + h];
        av = (av >= 0.f) ? av : 0.2f * av;
        wgt = expf(av - mx);
      }
      wsum += wgt;
      int cnt = o1 - pb; if (cnt > 8) cnt = 8;
      for (int j = 0; j < cnt; ++j) {
        float wA = __shfl(wgt, j * 8 + h0);
        float wB = __shfl(wgt, j * 8 + h3);
        int sj = __shfl(s, j * 8);
        if (val4) {
          f32x4 xv = *(const f32x4*)(xs + (size_t)sj * HD + c0);
#pragma unroll
          for (int i = 0; i < 4; ++i)
            acc[i] += ((i < bcut) ? wA : wB) * xv[i];
        }
      }
    }
    wsum += __shfl_xor(wsum, 8);
    wsum += __shfl_xor(wsum, 16);
    wsum += __shfl_xor(wsum, 32);
    // self contribution last (reference concat order)
    float wself = (lane < 8) ? expf(lself - mx) : 0.f;
    {
      float wA = __shfl(wself, h0);
      float wB = __shfl(wself, h3);
      if (val4) {
        f32x4 xv = *(const f32x4*)(xs + (size_t)node * HD + c0);
#pragma unroll
        for (int i = 0; i < 4; ++i)
          acc[i] += ((i < bcut) ? wA : wB) * xv[i];
      }
      wsum += __shfl(wself, h);
    }
    float denA = __shfl(wsum, h0) + 1e-16f;
    float denB = __shfl(wsum, h3) + 1e-16f;
    if (val4) {
      f32x4 gv = *(const f32x4*)(gb + c0);
      f32x4 hv;
#pragma unroll
      for (int i = 0; i < 4; ++i)
        hv[i] = acc[i] / ((i < bcut) ? denA : denB) + gv[i];
      if (writeH) *(f32x4*)(h_out + (size_t)node * HD + c0) = hv;
      pacc += hv;
    }
  }
  // cross-wave pooled reduction -> pooled[g][coff + c]
  if (val4) *(f32x4*)(&red[wv][c0]) = pacc;
  __syncthreads();
  if (wv == 0 && val4) {
    f32x4 r0 = *(const f32x4*)(&red[0][c0]);
    f32x4 r1 = *(const f32x4*)(&red[1][c0]);
    f32x4 r2 = *(const f32x4*)(&red[2][c0]);
    f32x4 r3 = *(const f32x4*)(&red[3][c0]);
    f32x4 s = (r0 + r1) + (r2 + r3);
    *(f32x4*)(pooled + (size_t)g * 800 + coff + c0) = s;
  }
}

__global__ __launch_bounds__(256) void k_gstart(const int* __restrict__ batch, int* __restrict__ gstart,
                                                int N, int G) {
  int i = blockIdx.x * 256 + threadIdx.x;
  if (i >= N) return;
  int b = batch[i];
  int pb = (i == 0) ? -1 : batch[i - 1];
  for (int g = pb + 1; g <= b; ++g) gstart[g] = i;
  if (i == N - 1) for (int g = b + 1; g <= G; ++g) gstart[g] = N;
}

extern "C" void kernel_launch(void* const* d_in, const int* in_sizes, int n_in,
                              void* d_out, int out_size, void* d_ws, size_t ws_size,
                              hipStream_t stream) {
  const float* x         = (const float*)d_in[0];
  const float* edge_attr = (const float*)d_in[1];
  const float* node_w    = (const float*)d_in[2];
  const float* node_b    = (const float*)d_in[3];
  const float* edge_w    = (const float*)d_in[4];
  const float* edge_b    = (const float*)d_in[5];
  const float* lin_w     = (const float*)d_in[6];
  const float* lin_edge_w= (const float*)d_in[7];
  const float* att_src   = (const float*)d_in[8];
  const float* att_dst   = (const float*)d_in[9];
  const float* att_edge  = (const float*)d_in[10];
  const float* gat_bias  = (const float*)d_in[11];
  const float* readout_w = (const float*)d_in[12];
  const float* readout_b = (const float*)d_in[13];
  const float* head_w1   = (const float*)d_in[14];
  const float* head_b1   = (const float*)d_in[15];
  const float* head_w2   = (const float*)d_in[16];
  const float* head_b2   = (const float*)d_in[17];
  const int*   edge_index= (const int*)d_in[18];
  const int*   batch     = (const int*)d_in[19];

  const int N = in_sizes[0] / 64;
  const int E = in_sizes[1] / 6;
  const int G = out_size / 5;
  const int* srcI = edge_index;
  const int* dstI = edge_index + E;

  char* wsb = (char*)d_ws;
  size_t o = 0;
  auto alloc = [&](size_t bytes) -> void* {
    void* p = wsb + o;
    o = (o + bytes + 255) & ~(size_t)255;
    return p;
  };
  float* h       = (float*)alloc((size_t)N * HD * 4);
  float* xs      = (float*)alloc((size_t)N * HD * 4);
  float* a_src   = (float*)alloc((size_t)N * 8 * 4);
  float* a_dst   = (float*)alloc((size_t)N * 8 * 4);
  float* aep     = (float*)alloc((size_t)NL * E * 8 * 4);
  int*   src_csr = (int*)alloc((size_t)E * 4);
  float* ae_s    = (float*)alloc((size_t)NL * N * 8 * 4);
  float* mean_ea = (float*)alloc((size_t)N * 6 * 4);
  float* we      = (float*)alloc((size_t)NL * HD * 8 * 4);
  float* wsrc    = (float*)alloc((size_t)NL * HD * 8 * 4);
  float* wdst    = (float*)alloc((size_t)NL * HD * 8 * 4);
  float* Mm      = (float*)alloc((size_t)NL * 6 * 8 * 4);
  float* cv      = (float*)alloc((size_t)NL * 8 * 4);
  int* cnt       = (int*)alloc((size_t)N * 4);
  int* cur       = (int*)alloc((size_t)N * 4);
  int* off       = (int*)alloc((size_t)(N + 1) * 4);
  int* partial   = (int*)alloc(512 * 4);
  int* eid       = (int*)alloc((size_t)E * 4);
  int* gstart    = (int*)alloc((size_t)(G + 1) * 4);
  float* pooled4 = (float*)alloc((size_t)G * 800 * 4);
  float* readouts= (float*)alloc((size_t)G * HD * 4);
  float* bsum    = (float*)alloc(HD * 4);
  // pre-split LDS-image weight buffers (u32 = 2 bf16; 7168 u32 per K-step)
  u32* nodePk    = (u32*)alloc((size_t)2 * 7168 * 4);
  u32* linPk     = (u32*)alloc((size_t)NL * 7 * 7168 * 4);
  u32* roPk      = (u32*)alloc((size_t)25 * 7168 * 4);
  u32* hw_hi     = (u32*)alloc((size_t)5 * 112 * 112 * 4);
  u32* hw_lo     = (u32*)alloc((size_t)5 * 112 * 112 * 4);
  (void)ws_size; (void)n_in;

  hipMemsetAsync(cnt, 0, (size_t)N * 4, stream);
  hipMemsetAsync(cur, 0, (size_t)N * 4, stream);

  int nb = (N + 255) / 256;
  k_hist<<<(E + 255) / 256, 256, 0, stream>>>(dstI, cnt, E);
  k_scan1<<<nb, 256, 0, stream>>>(cnt, off, partial, N);
  k_scan2<<<1, 512, 0, stream>>>(partial, nb, off, N);
  k_scan3<<<nb, 256, 0, stream>>>(off, partial, N);
  k_scatter<<<(E + 255) / 256, 256, 0, stream>>>(dstI, off, cur, eid, E);
  k_sort<<<nb, 256, 0, stream>>>(off, eid, N);
  k_meanea<<<(N + 127) / 128, 128, 0, stream>>>(edge_attr, off, eid, mean_ea, N);
  k_we2<<<(NL * HD * 8 + 255) / 256, 256, 0, stream>>>(lin_edge_w, lin_w, att_edge, att_src, att_dst,
                                                       we, wsrc, wdst);
  k_M<<<1, 256, 0, stream>>>(edge_w, edge_b, we, Mm, cv);
  k_ae_self<<<(N + 255) / 256, 256, 0, stream>>>(mean_ea, cnt, Mm, cv, ae_s, N);
  k_aep<<<(E + 255) / 256, 256, 0, stream>>>(edge_attr, eid, srcI, Mm, cv, src_csr, aep, E);

  // weight splits
  {
    k_split5<<<dim3((2 * 7168 + 255) / 256, 1), 256, 0, stream>>>(node_w, nodePk, 64, 2, 0,
                                                                  nullptr, nullptr);
    k_split5<<<dim3((7 * 7168 + 255) / 256, NL), 256, 0, stream>>>(lin_w, linPk, HD, 7, HD * HD,
                                                                   wsrc, wdst);
    k_split_ro5<<<(25 * 7168 + 255) / 256, 256, 0, stream>>>(readout_w, roPk);
    k_bsum<<<1, 256, 0, stream>>>(readout_b, bsum);
    dim3 g3((112 * 112 + 255) / 256, 5);
    k_split_hw<<<g3, 256, 0, stream>>>(head_w1, hw_hi, hw_lo);
  }

  const int gemmBlocks = (N + 63) / 64;
  k_gemm_v5<2, false><<<gemmBlocks, 256, 0, stream>>>(x, nodePk, node_b, h, nullptr, nullptr, N, 64);
  k_gstart<<<nb, 256, 0, stream>>>(batch, gstart, N, G);

  for (int l = 0; l < NL; ++l) {
    k_gemm_v5<7, true><<<gemmBlocks, 256, 0, stream>>>(h, linPk + (size_t)l * 7 * 7168,
                                                       nullptr, xs, a_src, a_dst, N, HD);
    k_aggr4<<<G, 256, 0, stream>>>(xs, a_src, a_dst, aep + (size_t)l * E * 8,
                                   ae_s + (size_t)l * N * 8, gat_bias + l * HD,
                                   off, src_csr, gstart, h, pooled4, l * HD, (l < NL - 1) ? 1 : 0);
  }
  // merged readout: readouts = pooled4 @ roW4 + sum_l b_l   (K = 800)
  k_gemm_v5<25, false><<<(G + 63) / 64, 256, 0, stream>>>(pooled4, roPk, bsum, readouts,
                                                          nullptr, nullptr, G, 800);
  {
    dim3 hg((G + 63) / 64, 5);
    k_headgemm<<<hg, 128, 0, stream>>>(readouts, hw_hi, hw_lo, head_b1, head_w2, head_b2,
                                       (float*)d_out, G);
  }
}